// Round 1
// baseline (1102.441 us; speedup 1.0000x reference)
//
#include <hip/hip_runtime.h>
#include <hip/hip_bf16.h>
#include <math.h>

#define DIMSZ 1024
#define NHEAD 16
#define HDIM 64
#define BATCH 2
#define SEQ 2048
#define NROWS (BATCH * SEQ)   // 4096

// ---------------------------------------------------------------------------
// Tiled fp32 GEMM:  out[r, c] = sum_k A[r, k] * W[c, k] + bias[c]
// A: [NROWS, 1024] row-major; W: [1024, 1024] row-major (torch Linear weight)
// MODE 0: write out in [B, H, S, Dh] layout (for Q/K/V)
// MODE 1: write out row-major [NROWS, 1024]  (for final projection)
// 64x64 tile / block, 256 threads, 4x4 micro-tile per thread.
// ---------------------------------------------------------------------------
template <int MODE>
__global__ __launch_bounds__(256) void gemm_bias(
    const float* __restrict__ A, const float* __restrict__ W,
    const float* __restrict__ bias, float* __restrict__ out)
{
    // Transposed tiles: As[k][m], Bs[k][n]; row length 68 keeps float4
    // alignment and <=2-way bank aliasing (free on CDNA4).
    __shared__ float As[16][68];
    __shared__ float Bs[16][68];

    const int tid = threadIdx.x;
    const int tx = tid & 15;        // column group
    const int ty = tid >> 4;        // row group
    const int m0 = blockIdx.x * 64; // row tile origin
    const int n0 = blockIdx.y * 64; // col tile origin

    // loader mapping: each thread loads one float4 of A and one of W per chunk
    const int lr = tid >> 2;         // 0..63 (tile row)
    const int lk = (tid & 3) << 2;   // 0,4,8,12 (k offset)

    float acc[4][4] = {};

    for (int k0 = 0; k0 < DIMSZ; k0 += 16) {
        const float4 av = *(const float4*)&A[(size_t)(m0 + lr) * DIMSZ + k0 + lk];
        const float4 bv = *(const float4*)&W[(size_t)(n0 + lr) * DIMSZ + k0 + lk];
        __syncthreads();  // protect previous iteration's reads
        As[lk + 0][lr] = av.x; As[lk + 1][lr] = av.y;
        As[lk + 2][lr] = av.z; As[lk + 3][lr] = av.w;
        Bs[lk + 0][lr] = bv.x; Bs[lk + 1][lr] = bv.y;
        Bs[lk + 2][lr] = bv.z; Bs[lk + 3][lr] = bv.w;
        __syncthreads();
#pragma unroll
        for (int k = 0; k < 16; ++k) {
            const float4 a4 = *(const float4*)&As[k][ty << 2];
            const float4 b4 = *(const float4*)&Bs[k][tx << 2];
            const float a[4] = {a4.x, a4.y, a4.z, a4.w};
            const float b[4] = {b4.x, b4.y, b4.z, b4.w};
#pragma unroll
            for (int i = 0; i < 4; ++i)
#pragma unroll
                for (int j = 0; j < 4; ++j)
                    acc[i][j] = fmaf(a[i], b[j], acc[i][j]);
        }
    }

    const float4 bias4 = *(const float4*)&bias[n0 + (tx << 2)];
    const float bb[4] = {bias4.x, bias4.y, bias4.z, bias4.w};

#pragma unroll
    for (int i = 0; i < 4; ++i) {
        const int n = m0 + (ty << 2) + i;      // global row (b*SEQ + s)
        if (MODE == 0) {
            // out[((b*NHEAD + h)*SEQ + s)*HDIM + d]
            const int b = n >> 11;
            const int s = n & (SEQ - 1);
            const int c0 = n0 + (tx << 2);     // head-aligned tile: h fixed
            const int h = c0 >> 6;
            const int d = c0 & 63;
            float4 o4 = make_float4(acc[i][0] + bb[0], acc[i][1] + bb[1],
                                    acc[i][2] + bb[2], acc[i][3] + bb[3]);
            *(float4*)&out[((size_t)(b * NHEAD + h) * SEQ + s) * HDIM + d] = o4;
        } else {
            float4 o4 = make_float4(acc[i][0] + bb[0], acc[i][1] + bb[1],
                                    acc[i][2] + bb[2], acc[i][3] + bb[3]);
            *(float4*)&out[(size_t)n * DIMSZ + n0 + (tx << 2)] = o4;
        }
    }
}

// ---------------------------------------------------------------------------
// Flash attention (fp32, online softmax).
// Grid: (SEQ/64, BATCH*NHEAD). Block: 256 threads.
// Each block: 64 queries of one (b,h); loops over 32 chunks of 64 keys.
// ---------------------------------------------------------------------------
__global__ __launch_bounds__(256) void flash_attn(
    const float* __restrict__ Q, const float* __restrict__ K,
    const float* __restrict__ V, float* __restrict__ CTX)
{
    __shared__ float Qs[64][68];   // [k][query-row]  (transposed)
    __shared__ float Ks[64][68];   // [k][key-col]    (transposed)
    __shared__ float Vs[64][68];   // [key][d]        (natural)
    __shared__ float Ps[64][68];   // [query][key]    (natural)
    __shared__ float red[64][17];
    __shared__ float mprev[64], lsum[64], alpha_s[64], mnew[64];

    const int tid = threadIdx.x;
    const int tx = tid & 15;
    const int ty = tid >> 4;
    const int q0 = blockIdx.x * 64;
    const int bh = blockIdx.y;               // b*NHEAD + h
    const float scale = 0.125f;              // 1/sqrt(64)

    const float* Qbase = Q + ((size_t)bh * SEQ + q0) * HDIM;
    const float* Kbase = K + (size_t)bh * SEQ * HDIM;
    const float* Vbase = V + (size_t)bh * SEQ * HDIM;

    // Load Q tile transposed: Qs[k][row]
    {
        const int r = tid >> 2;
        const int kb = (tid & 3) << 2;
#pragma unroll
        for (int p = 0; p < 4; ++p) {
            const int kk = kb + (p << 4);
            const float4 v4 = *(const float4*)&Qbase[(size_t)r * HDIM + kk];
            Qs[kk + 0][r] = v4.x; Qs[kk + 1][r] = v4.y;
            Qs[kk + 2][r] = v4.z; Qs[kk + 3][r] = v4.w;
        }
    }
    if (tid < 64) { mprev[tid] = -1e30f; lsum[tid] = 0.0f; }

    float o[4][4] = {};

    for (int kc = 0; kc < SEQ; kc += 64) {
        __syncthreads();  // protect Ks/Vs/Ps/red from previous iteration
        {
            const int r = tid >> 2;
            const int kb = (tid & 3) << 2;
#pragma unroll
            for (int p = 0; p < 4; ++p) {
                const int kk = kb + (p << 4);
                const float4 kv = *(const float4*)&Kbase[(size_t)(kc + r) * HDIM + kk];
                Ks[kk + 0][r] = kv.x; Ks[kk + 1][r] = kv.y;
                Ks[kk + 2][r] = kv.z; Ks[kk + 3][r] = kv.w;
                *(float4*)&Vs[r][kk] = *(const float4*)&Vbase[(size_t)(kc + r) * HDIM + kk];
            }
        }
        __syncthreads();

        // scores: sc[i][j] = q(4ty+i) . k(4tx+j)
        float sc[4][4] = {};
#pragma unroll 8
        for (int k = 0; k < 64; ++k) {
            const float4 a4 = *(const float4*)&Qs[k][ty << 2];
            const float4 b4 = *(const float4*)&Ks[k][tx << 2];
            const float a[4] = {a4.x, a4.y, a4.z, a4.w};
            const float b[4] = {b4.x, b4.y, b4.z, b4.w};
#pragma unroll
            for (int i = 0; i < 4; ++i)
#pragma unroll
                for (int j = 0; j < 4; ++j)
                    sc[i][j] = fmaf(a[i], b[j], sc[i][j]);
        }
#pragma unroll
        for (int i = 0; i < 4; ++i)
#pragma unroll
            for (int j = 0; j < 4; ++j) sc[i][j] *= scale;

        // per-thread row max -> LDS reduce
#pragma unroll
        for (int i = 0; i < 4; ++i) {
            float m = sc[i][0];
#pragma unroll
            for (int j = 1; j < 4; ++j) m = fmaxf(m, sc[i][j]);
            red[(ty << 2) + i][tx] = m;
        }
        __syncthreads();
        if (tid < 64) {
            float m = red[tid][0];
#pragma unroll
            for (int t = 1; t < 16; ++t) m = fmaxf(m, red[tid][t]);
            const float mp = mprev[tid];
            const float mn = fmaxf(mp, m);
            mnew[tid] = mn;
            alpha_s[tid] = __expf(mp - mn);
            mprev[tid] = mn;
        }
        __syncthreads();

        // p = exp(s - mnew); write Ps; partial row sums
#pragma unroll
        for (int i = 0; i < 4; ++i) {
            const float mn = mnew[(ty << 2) + i];
            float acc = 0.0f;
#pragma unroll
            for (int j = 0; j < 4; ++j) {
                const float p = __expf(sc[i][j] - mn);
                Ps[(ty << 2) + i][(tx << 2) + j] = p;
                acc += p;
            }
            red[(ty << 2) + i][tx] = acc;
        }
        __syncthreads();
        if (tid < 64) {
            float r = 0.0f;
#pragma unroll
            for (int t = 0; t < 16; ++t) r += red[tid][t];
            lsum[tid] = lsum[tid] * alpha_s[tid] + r;
        }

        // O = O*alpha + P @ V
        float alv[4];
#pragma unroll
        for (int i = 0; i < 4; ++i) alv[i] = alpha_s[(ty << 2) + i];
#pragma unroll
        for (int i = 0; i < 4; ++i)
#pragma unroll
            for (int d = 0; d < 4; ++d) o[i][d] *= alv[i];

#pragma unroll 4
        for (int jb = 0; jb < 64; jb += 4) {
            float4 a4[4], b4[4];
#pragma unroll
            for (int i = 0; i < 4; ++i) a4[i] = *(const float4*)&Ps[(ty << 2) + i][jb];
#pragma unroll
            for (int dj = 0; dj < 4; ++dj) b4[dj] = *(const float4*)&Vs[jb + dj][tx << 2];
#pragma unroll
            for (int i = 0; i < 4; ++i) {
                const float a[4] = {a4[i].x, a4[i].y, a4[i].z, a4[i].w};
#pragma unroll
                for (int dj = 0; dj < 4; ++dj) {
                    const float b[4] = {b4[dj].x, b4[dj].y, b4[dj].z, b4[dj].w};
#pragma unroll
                    for (int d = 0; d < 4; ++d)
                        o[i][d] = fmaf(a[dj], b[d], o[i][d]);
                }
            }
        }
    }
    __syncthreads();  // ensure final lsum visible

    const int b = bh >> 4;
    const int h = bh & 15;
#pragma unroll
    for (int i = 0; i < 4; ++i) {
        const float linv = 1.0f / lsum[(ty << 2) + i];
        const int n = b * SEQ + q0 + (ty << 2) + i;
        float4 o4 = make_float4(o[i][0] * linv, o[i][1] * linv,
                                o[i][2] * linv, o[i][3] * linv);
        *(float4*)&CTX[(size_t)n * DIMSZ + h * HDIM + (tx << 2)] = o4;
    }
}

// ---------------------------------------------------------------------------
extern "C" void kernel_launch(void* const* d_in, const int* in_sizes, int n_in,
                              void* d_out, int out_size, void* d_ws, size_t ws_size,
                              hipStream_t stream)
{
    const float* x  = (const float*)d_in[0];
    const float* Wq = (const float*)d_in[1];
    const float* bq = (const float*)d_in[2];
    const float* Wk = (const float*)d_in[3];
    const float* bk = (const float*)d_in[4];
    const float* Wv = (const float*)d_in[5];
    const float* bv = (const float*)d_in[6];
    const float* Wo = (const float*)d_in[7];
    const float* bo = (const float*)d_in[8];
    float* out = (float*)d_out;

    const size_t elems = (size_t)NROWS * DIMSZ;  // 4,194,304
    float* Qw  = (float*)d_ws;
    float* Kw  = Qw + elems;
    float* Vw  = Kw + elems;
    float* CTX = Vw + elems;

    dim3 gemm_grid(NROWS / 64, DIMSZ / 64);
    dim3 blk(256);

    gemm_bias<0><<<gemm_grid, blk, 0, stream>>>(x, Wq, bq, Qw);
    gemm_bias<0><<<gemm_grid, blk, 0, stream>>>(x, Wk, bk, Kw);
    gemm_bias<0><<<gemm_grid, blk, 0, stream>>>(x, Wv, bv, Vw);

    dim3 attn_grid(SEQ / 64, BATCH * NHEAD);
    flash_attn<<<attn_grid, blk, 0, stream>>>(Qw, Kw, Vw, CTX);

    gemm_bias<1><<<gemm_grid, blk, 0, stream>>>(CTX, Wo, bo, out);
}

// Round 2
// 715.119 us; speedup vs baseline: 1.5416x; 1.5416x over previous
//
#include <hip/hip_runtime.h>
#include <hip/hip_bf16.h>
#include <math.h>

#define DIMSZ 1024
#define NHEAD 16
#define HDIM 64
#define BATCH 2
#define SEQ 2048
#define NROWS (BATCH * SEQ)   // 4096

typedef __attribute__((ext_vector_type(8))) short bf16x8;
typedef __attribute__((ext_vector_type(4))) float f32x4;

// LDS chunk swizzle: sigma(m) for m in [0,16); chunk slot = data_chunk ^ sigma.
// Gives uniform bank-group coverage for the mfma frag-read pattern
// (lane m=l&15, quad q=l>>4): (4m + q^sigma(m)) mod 8 hits each group evenly.
__device__ __forceinline__ int swz(int m) { return (m ^ (m >> 2)) & 3; }

// pack high-16 bits of two fp32 dwords: low ushort = a>>16, high ushort = b>>16
__device__ __forceinline__ unsigned hipack(unsigned a, unsigned b) {
    return __builtin_amdgcn_perm(b, a, 0x07060302u);
}

// truncation split of 2 floats into bf16 hi-pair and lo-pair (packed dwords).
// hi = trunc-to-bf16(x); resid = x - hi (exact); lo = trunc-to-bf16(resid).
// total representation error ~2^-16 relative — negligible vs fp32 baseline.
__device__ __forceinline__ void cvt2(float x, float y, unsigned& h, unsigned& l) {
    unsigned ux = __float_as_uint(x), uy = __float_as_uint(y);
    h = hipack(ux, uy);
    float rx = x - __uint_as_float(ux & 0xFFFF0000u);
    float ry = y - __uint_as_float(uy & 0xFFFF0000u);
    l = hipack(__float_as_uint(rx), __float_as_uint(ry));
}

// convert 8 consecutive floats (two float4) -> uint4 hi (8 bf16), uint4 lo
__device__ __forceinline__ void cvt8(const float4& f0, const float4& f1,
                                     uint4& hv, uint4& lv) {
    cvt2(f0.x, f0.y, hv.x, lv.x);
    cvt2(f0.z, f0.w, hv.y, lv.y);
    cvt2(f1.x, f1.y, hv.z, lv.z);
    cvt2(f1.z, f1.w, hv.w, lv.w);
}

__device__ __forceinline__ void gld16(const void* g, void* l) {
    __builtin_amdgcn_global_load_lds((const __attribute__((address_space(1))) void*)g,
                                     (__attribute__((address_space(3))) void*)l,
                                     16, 0, 0);
}

// ---------------------------------------------------------------------------
// convert fp32 weight matrix [1024x1024] -> hi/lo bf16 arrays (trunc split)
// grid 512 x 256 threads, 8 elems/thread
// ---------------------------------------------------------------------------
__global__ __launch_bounds__(256) void convert_w(
    const float* __restrict__ src, ushort* __restrict__ hi, ushort* __restrict__ lo)
{
    const int i = (blockIdx.x * 256 + threadIdx.x) * 8;
    const float4 f0 = *(const float4*)&src[i];
    const float4 f1 = *(const float4*)&src[i + 4];
    uint4 hv, lv;
    cvt8(f0, f1, hv, lv);
    *(uint4*)&hi[i] = hv;
    *(uint4*)&lo[i] = lv;
}

// ---------------------------------------------------------------------------
// Fused QKV GEMM (split-bf16 MFMA).
// C[m, n] = sum_k X[m,k] * W[n,k] + bias[n], n in [0,3072) spanning Wq|Wk|Wv.
// Block tile 128x128, BK=32, 256 threads = 4 waves (2x2), wave tile 64x64
// = 4x4 grid of 16x16x32 MFMAs, 3 MFMAs per tile per kstep (hi*hi+hi*lo+lo*hi).
// A (x fp32): loaded to regs, trunc-split, ds_write to swizzled LDS.
// B (Whi/Wlo pre-converted): global_load_lds width=16, swizzle applied on the
//   global chunk index (keeps 64B-segment coalescing).
// Output written in [B,H,S,Dh] layout for flash_attn.
// ---------------------------------------------------------------------------
__global__ __launch_bounds__(256) void qkv_gemm(
    const float* __restrict__ X,       // [4096][1024]
    const ushort* __restrict__ Whi,    // [3072][1024] bf16 bits
    const ushort* __restrict__ Wlo,
    const float* __restrict__ bq, const float* __restrict__ bk,
    const float* __restrict__ bv,
    float* __restrict__ Q, float* __restrict__ K, float* __restrict__ V)
{
    __shared__ __align__(16) ushort Ahi[128 * 32];
    __shared__ __align__(16) ushort Alo[128 * 32];
    __shared__ __align__(16) ushort Bhi[128 * 32];
    __shared__ __align__(16) ushort Blo[128 * 32];

    const int tid = threadIdx.x;
    const int wave = tid >> 6;
    const int lane = tid & 63;
    const int lm = lane & 15;
    const int lq = lane >> 4;
    const int wy = wave >> 1;   // m half
    const int wx = wave & 1;    // n half
    const int m0 = blockIdx.x * 128;
    const int nbase = blockIdx.y * 128;   // global n (0..3071)

    // --- A staging (register convert path): thread -> row r, half h (16 floats)
    const int ar = tid >> 1;
    const int ah_ = tid & 1;
    const float* ap = X + (size_t)(m0 + ar) * DIMSZ + ah_ * 16;
    const int wr0 = ar * 32 + (((ah_ * 2 + 0) ^ swz(ar & 15)) << 3);
    const int wr1 = ar * 32 + (((ah_ * 2 + 1) ^ swz(ar & 15)) << 3);

    // --- B staging (global_load_lds): thread -> row r0 / r0+64, chunk c
    const int c = tid & 3;
    const int r0 = tid >> 2;
    const int g = c ^ swz(r0 & 15);
    const ushort* gbh = Whi + (size_t)(nbase + r0) * DIMSZ + g * 8;
    const ushort* gbl = Wlo + (size_t)(nbase + r0) * DIMSZ + g * 8;
    ushort* lbh0 = &Bhi[wave * 512];
    ushort* lbh1 = &Bhi[2048 + wave * 512];
    ushort* lbl0 = &Blo[wave * 512];
    ushort* lbl1 = &Blo[2048 + wave * 512];

    // --- frag read offsets
    const int fo = lm * 32 + (((lq ^ swz(lm)) & 3) << 3);
    int aofs[4], bofs[4];
#pragma unroll
    for (int i = 0; i < 4; ++i) {
        aofs[i] = (wy * 64 + i * 16) * 32 + fo;
        bofs[i] = (wx * 64 + i * 16) * 32 + fo;
    }

    f32x4 acc[4][4] = {};

    for (int k0 = 0; k0 < DIMSZ; k0 += 32) {
        const float4 f0 = *(const float4*)(ap + k0 + 0);
        const float4 f1 = *(const float4*)(ap + k0 + 4);
        const float4 f2 = *(const float4*)(ap + k0 + 8);
        const float4 f3 = *(const float4*)(ap + k0 + 12);

        __syncthreads();   // previous iteration's frag reads complete

        gld16(gbh + k0, lbh0);
        gld16(gbh + 64 * DIMSZ + k0, lbh1);
        gld16(gbl + k0, lbl0);
        gld16(gbl + 64 * DIMSZ + k0, lbl1);

        uint4 hv0, lv0, hv1, lv1;
        cvt8(f0, f1, hv0, lv0);
        cvt8(f2, f3, hv1, lv1);
        *(uint4*)&Ahi[wr0] = hv0;
        *(uint4*)&Ahi[wr1] = hv1;
        *(uint4*)&Alo[wr0] = lv0;
        *(uint4*)&Alo[wr1] = lv1;

        __syncthreads();   // staging (vmcnt for lds-DMA + lgkm for ds_write) done

        bf16x8 ahf[4], alf[4], bhf[4], blf[4];
#pragma unroll
        for (int i = 0; i < 4; ++i) {
            ahf[i] = *(const bf16x8*)&Ahi[aofs[i]];
            alf[i] = *(const bf16x8*)&Alo[aofs[i]];
            bhf[i] = *(const bf16x8*)&Bhi[bofs[i]];
            blf[i] = *(const bf16x8*)&Blo[bofs[i]];
        }
#pragma unroll
        for (int i = 0; i < 4; ++i)
#pragma unroll
            for (int j = 0; j < 4; ++j) {
                acc[i][j] = __builtin_amdgcn_mfma_f32_16x16x32_bf16(ahf[i], bhf[j], acc[i][j], 0, 0, 0);
                acc[i][j] = __builtin_amdgcn_mfma_f32_16x16x32_bf16(ahf[i], blf[j], acc[i][j], 0, 0, 0);
                acc[i][j] = __builtin_amdgcn_mfma_f32_16x16x32_bf16(alf[i], bhf[j], acc[i][j], 0, 0, 0);
            }
    }

    // --- epilogue: C/D layout col=lane&15, row=(lane>>4)*4+reg (m89-verified)
    const int mat = blockIdx.y >> 3;   // 0:Q 1:K 2:V (uniform per block)
    const float* bias = (mat == 0) ? bq : (mat == 1) ? bk : bv;
    float* outp = (mat == 0) ? Q : (mat == 1) ? K : V;
    const int nloc0 = (blockIdx.y & 7) * 128;

#pragma unroll
    for (int j = 0; j < 4; ++j) {
        const int nc = nloc0 + wx * 64 + j * 16 + lm;   // 0..1023
        const float bb = bias[nc];
        const int h = nc >> 6;
        const int d = nc & 63;
#pragma unroll
        for (int i = 0; i < 4; ++i) {
            const int mb = m0 + wy * 64 + i * 16 + lq * 4;
#pragma unroll
            for (int rr = 0; rr < 4; ++rr) {
                const int m = mb + rr;
                const int b = m >> 11;
                const int s = m & (SEQ - 1);
                outp[(((size_t)b * NHEAD + h) * SEQ + s) * HDIM + d] = acc[i][j][rr] + bb;
            }
        }
    }
}

// ---------------------------------------------------------------------------
// Output projection GEMM (split-bf16 MFMA), both operands fp32->converted
// in-kernel (CTX is produced fp32 by flash_attn; Wo stays fp32 to save ws).
// out[m, n] = sum_k CTX[m,k] * Wo[n,k] + bo[n], row-major out.
// ---------------------------------------------------------------------------
__global__ __launch_bounds__(256) void oproj_gemm(
    const float* __restrict__ A,       // CTX [4096][1024]
    const float* __restrict__ W,       // Wo  [1024][1024]
    const float* __restrict__ bias,
    float* __restrict__ out)
{
    __shared__ __align__(16) ushort Ahi[128 * 32];
    __shared__ __align__(16) ushort Alo[128 * 32];
    __shared__ __align__(16) ushort Bhi[128 * 32];
    __shared__ __align__(16) ushort Blo[128 * 32];

    const int tid = threadIdx.x;
    const int wave = tid >> 6;
    const int lane = tid & 63;
    const int lm = lane & 15;
    const int lq = lane >> 4;
    const int wy = wave >> 1;
    const int wx = wave & 1;
    const int m0 = blockIdx.x * 128;
    const int n0 = blockIdx.y * 128;

    const int ar = tid >> 1;
    const int ah_ = tid & 1;
    const float* ap = A + (size_t)(m0 + ar) * DIMSZ + ah_ * 16;
    const float* bp = W + (size_t)(n0 + ar) * DIMSZ + ah_ * 16;
    const int wr0 = ar * 32 + (((ah_ * 2 + 0) ^ swz(ar & 15)) << 3);
    const int wr1 = ar * 32 + (((ah_ * 2 + 1) ^ swz(ar & 15)) << 3);

    const int fo = lm * 32 + (((lq ^ swz(lm)) & 3) << 3);
    int aofs[4], bofs[4];
#pragma unroll
    for (int i = 0; i < 4; ++i) {
        aofs[i] = (wy * 64 + i * 16) * 32 + fo;
        bofs[i] = (wx * 64 + i * 16) * 32 + fo;
    }

    f32x4 acc[4][4] = {};

    for (int k0 = 0; k0 < DIMSZ; k0 += 32) {
        const float4 a0 = *(const float4*)(ap + k0 + 0);
        const float4 a1 = *(const float4*)(ap + k0 + 4);
        const float4 a2 = *(const float4*)(ap + k0 + 8);
        const float4 a3 = *(const float4*)(ap + k0 + 12);
        const float4 b0 = *(const float4*)(bp + k0 + 0);
        const float4 b1 = *(const float4*)(bp + k0 + 4);
        const float4 b2 = *(const float4*)(bp + k0 + 8);
        const float4 b3 = *(const float4*)(bp + k0 + 12);

        __syncthreads();

        uint4 hv, lv;
        cvt8(a0, a1, hv, lv); *(uint4*)&Ahi[wr0] = hv; *(uint4*)&Alo[wr0] = lv;
        cvt8(a2, a3, hv, lv); *(uint4*)&Ahi[wr1] = hv; *(uint4*)&Alo[wr1] = lv;
        cvt8(b0, b1, hv, lv); *(uint4*)&Bhi[wr0] = hv; *(uint4*)&Blo[wr0] = lv;
        cvt8(b2, b3, hv, lv); *(uint4*)&Bhi[wr1] = hv; *(uint4*)&Blo[wr1] = lv;

        __syncthreads();

        bf16x8 ahf[4], alf[4], bhf[4], blf[4];
#pragma unroll
        for (int i = 0; i < 4; ++i) {
            ahf[i] = *(const bf16x8*)&Ahi[aofs[i]];
            alf[i] = *(const bf16x8*)&Alo[aofs[i]];
            bhf[i] = *(const bf16x8*)&Bhi[bofs[i]];
            blf[i] = *(const bf16x8*)&Blo[bofs[i]];
        }
#pragma unroll
        for (int i = 0; i < 4; ++i)
#pragma unroll
            for (int j = 0; j < 4; ++j) {
                acc[i][j] = __builtin_amdgcn_mfma_f32_16x16x32_bf16(ahf[i], bhf[j], acc[i][j], 0, 0, 0);
                acc[i][j] = __builtin_amdgcn_mfma_f32_16x16x32_bf16(ahf[i], blf[j], acc[i][j], 0, 0, 0);
                acc[i][j] = __builtin_amdgcn_mfma_f32_16x16x32_bf16(alf[i], bhf[j], acc[i][j], 0, 0, 0);
            }
    }

#pragma unroll
    for (int j = 0; j < 4; ++j) {
        const int nc = n0 + wx * 64 + j * 16 + lm;
        const float bb = bias[nc];
#pragma unroll
        for (int i = 0; i < 4; ++i) {
            const int mb = m0 + wy * 64 + i * 16 + lq * 4;
#pragma unroll
            for (int rr = 0; rr < 4; ++rr)
                out[(size_t)(mb + rr) * DIMSZ + nc] = acc[i][j][rr] + bb;
        }
    }
}

// ---------------------------------------------------------------------------
// Flash attention (fp32, online softmax) — unchanged from round 1.
// ---------------------------------------------------------------------------
__global__ __launch_bounds__(256) void flash_attn(
    const float* __restrict__ Q, const float* __restrict__ K,
    const float* __restrict__ V, float* __restrict__ CTX)
{
    __shared__ float Qs[64][68];
    __shared__ float Ks[64][68];
    __shared__ float Vs[64][68];
    __shared__ float Ps[64][68];
    __shared__ float red[64][17];
    __shared__ float mprev[64], lsum[64], alpha_s[64], mnew[64];

    const int tid = threadIdx.x;
    const int tx = tid & 15;
    const int ty = tid >> 4;
    const int q0 = blockIdx.x * 64;
    const int bh = blockIdx.y;
    const float scale = 0.125f;

    const float* Qbase = Q + ((size_t)bh * SEQ + q0) * HDIM;
    const float* Kbase = K + (size_t)bh * SEQ * HDIM;
    const float* Vbase = V + (size_t)bh * SEQ * HDIM;

    {
        const int r = tid >> 2;
        const int kb = (tid & 3) << 2;
#pragma unroll
        for (int p = 0; p < 4; ++p) {
            const int kk = kb + (p << 4);
            const float4 v4 = *(const float4*)&Qbase[(size_t)r * HDIM + kk];
            Qs[kk + 0][r] = v4.x; Qs[kk + 1][r] = v4.y;
            Qs[kk + 2][r] = v4.z; Qs[kk + 3][r] = v4.w;
        }
    }
    if (tid < 64) { mprev[tid] = -1e30f; lsum[tid] = 0.0f; }

    float o[4][4] = {};

    for (int kc = 0; kc < SEQ; kc += 64) {
        __syncthreads();
        {
            const int r = tid >> 2;
            const int kb = (tid & 3) << 2;
#pragma unroll
            for (int p = 0; p < 4; ++p) {
                const int kk = kb + (p << 4);
                const float4 kv = *(const float4*)&Kbase[(size_t)(kc + r) * HDIM + kk];
                Ks[kk + 0][r] = kv.x; Ks[kk + 1][r] = kv.y;
                Ks[kk + 2][r] = kv.z; Ks[kk + 3][r] = kv.w;
                *(float4*)&Vs[r][kk] = *(const float4*)&Vbase[(size_t)(kc + r) * HDIM + kk];
            }
        }
        __syncthreads();

        float sc[4][4] = {};
#pragma unroll 8
        for (int k = 0; k < 64; ++k) {
            const float4 a4 = *(const float4*)&Qs[k][ty << 2];
            const float4 b4 = *(const float4*)&Ks[k][tx << 2];
            const float a[4] = {a4.x, a4.y, a4.z, a4.w};
            const float b[4] = {b4.x, b4.y, b4.z, b4.w};
#pragma unroll
            for (int i = 0; i < 4; ++i)
#pragma unroll
                for (int j = 0; j < 4; ++j)
                    sc[i][j] = fmaf(a[i], b[j], sc[i][j]);
        }
#pragma unroll
        for (int i = 0; i < 4; ++i)
#pragma unroll
            for (int j = 0; j < 4; ++j) sc[i][j] *= scale;

#pragma unroll
        for (int i = 0; i < 4; ++i) {
            float m = sc[i][0];
#pragma unroll
            for (int j = 1; j < 4; ++j) m = fmaxf(m, sc[i][j]);
            red[(ty << 2) + i][tx] = m;
        }
        __syncthreads();
        if (tid < 64) {
            float m = red[tid][0];
#pragma unroll
            for (int t = 1; t < 16; ++t) m = fmaxf(m, red[tid][t]);
            const float mp = mprev[tid];
            const float mn = fmaxf(mp, m);
            mnew[tid] = mn;
            alpha_s[tid] = __expf(mp - mn);
            mprev[tid] = mn;
        }
        __syncthreads();

#pragma unroll
        for (int i = 0; i < 4; ++i) {
            const float mn = mnew[(ty << 2) + i];
            float acc = 0.0f;
#pragma unroll
            for (int j = 0; j < 4; ++j) {
                const float p = __expf(sc[i][j] - mn);
                Ps[(ty << 2) + i][(tx << 2) + j] = p;
                acc += p;
            }
            red[(ty << 2) + i][tx] = acc;
        }
        __syncthreads();
        if (tid < 64) {
            float r = 0.0f;
#pragma unroll
            for (int t = 0; t < 16; ++t) r += red[tid][t];
            lsum[tid] = lsum[tid] * alpha_s[tid] + r;
        }

        float alv[4];
#pragma unroll
        for (int i = 0; i < 4; ++i) alv[i] = alpha_s[(ty << 2) + i];
#pragma unroll
        for (int i = 0; i < 4; ++i)
#pragma unroll
            for (int d = 0; d < 4; ++d) o[i][d] *= alv[i];

#pragma unroll 4
        for (int jb = 0; jb < 64; jb += 4) {
            float4 a4[4], b4[4];
#pragma unroll
            for (int i = 0; i < 4; ++i) a4[i] = *(const float4*)&Ps[(ty << 2) + i][jb];
#pragma unroll
            for (int dj = 0; dj < 4; ++dj) b4[dj] = *(const float4*)&Vs[jb + dj][tx << 2];
#pragma unroll
            for (int i = 0; i < 4; ++i) {
                const float a[4] = {a4[i].x, a4[i].y, a4[i].z, a4[i].w};
#pragma unroll
                for (int dj = 0; dj < 4; ++dj) {
                    const float b[4] = {b4[dj].x, b4[dj].y, b4[dj].z, b4[dj].w};
#pragma unroll
                    for (int d = 0; d < 4; ++d)
                        o[i][d] = fmaf(a[dj], b[d], o[i][d]);
                }
            }
        }
    }
    __syncthreads();

    const int b = bh >> 4;
    const int h = bh & 15;
#pragma unroll
    for (int i = 0; i < 4; ++i) {
        const float linv = 1.0f / lsum[(ty << 2) + i];
        const int n = b * SEQ + q0 + (ty << 2) + i;
        float4 o4 = make_float4(o[i][0] * linv, o[i][1] * linv,
                                o[i][2] * linv, o[i][3] * linv);
        *(float4*)&CTX[(size_t)n * DIMSZ + h * HDIM + (tx << 2)] = o4;
    }
}

// ---------------------------------------------------------------------------
extern "C" void kernel_launch(void* const* d_in, const int* in_sizes, int n_in,
                              void* d_out, int out_size, void* d_ws, size_t ws_size,
                              hipStream_t stream)
{
    const float* x  = (const float*)d_in[0];
    const float* Wq = (const float*)d_in[1];
    const float* bq = (const float*)d_in[2];
    const float* Wk = (const float*)d_in[3];
    const float* bk = (const float*)d_in[4];
    const float* Wv = (const float*)d_in[5];
    const float* bv = (const float*)d_in[6];
    const float* Wo = (const float*)d_in[7];
    const float* bo = (const float*)d_in[8];
    float* out = (float*)d_out;

    const size_t elems = (size_t)NROWS * DIMSZ;   // 4M
    float* Qw  = (float*)d_ws;
    float* Kw  = Qw + elems;
    float* Vw  = Kw + elems;
    float* CTX = Vw + elems;                      // 16MB region at +48MB
    // W hi/lo converts overlay the CTX region (dead once qkv_gemm completes,
    // CTX only written afterwards by flash_attn). Peak ws use = 64MB.
    ushort* Whi = (ushort*)CTX;                   // 3M ushorts (6MB)
    ushort* Wlo = Whi + 3 * (1 << 20);            // 3M ushorts (6MB)

    convert_w<<<512, 256, 0, stream>>>(Wq, Whi, Wlo);
    convert_w<<<512, 256, 0, stream>>>(Wk, Whi + (1 << 20), Wlo + (1 << 20));
    convert_w<<<512, 256, 0, stream>>>(Wv, Whi + 2 * (1 << 20), Wlo + 2 * (1 << 20));

    qkv_gemm<<<dim3(32, 24), 256, 0, stream>>>(x, Whi, Wlo, bq, bk, bv, Qw, Kw, Vw);

    flash_attn<<<dim3(SEQ / 64, BATCH * NHEAD), 256, 0, stream>>>(Qw, Kw, Vw, CTX);

    oproj_gemm<<<dim3(32, 8), 256, 0, stream>>>(CTX, Wo, bo, out);
}

// Round 3
// 360.619 us; speedup vs baseline: 3.0571x; 1.9830x over previous
//
#include <hip/hip_runtime.h>
#include <hip/hip_bf16.h>
#include <math.h>

#define DIMSZ 1024
#define NHEAD 16
#define HDIM 64
#define BATCH 2
#define SEQ 2048
#define NROWS (BATCH * SEQ)   // 4096

// softmax runs in exp2 domain: fold 1/sqrt(64) * log2(e) into Q at conversion
#define QSCALE 0.18033688011112042592f

typedef __attribute__((ext_vector_type(8))) short bf16x8;
typedef __attribute__((ext_vector_type(4))) float f32x4;

__device__ __forceinline__ int swz(int m) { return (m ^ (m >> 2)) & 3; }

__device__ __forceinline__ unsigned hipack(unsigned a, unsigned b) {
    return __builtin_amdgcn_perm(b, a, 0x07060302u);
}

// truncation split: hi = trunc-bf16(x), lo = trunc-bf16(x - hi)
__device__ __forceinline__ void cvt2(float x, float y, unsigned& h, unsigned& l) {
    unsigned ux = __float_as_uint(x), uy = __float_as_uint(y);
    h = hipack(ux, uy);
    float rx = x - __uint_as_float(ux & 0xFFFF0000u);
    float ry = y - __uint_as_float(uy & 0xFFFF0000u);
    l = hipack(__float_as_uint(rx), __float_as_uint(ry));
}

__device__ __forceinline__ void cvt8(const float4& f0, const float4& f1,
                                     uint4& hv, uint4& lv) {
    cvt2(f0.x, f0.y, hv.x, lv.x);
    cvt2(f0.z, f0.w, hv.y, lv.y);
    cvt2(f1.x, f1.y, hv.z, lv.z);
    cvt2(f1.z, f1.w, hv.w, lv.w);
}

// RNE float -> bf16 bits
__device__ __forceinline__ ushort f2bf(float x) {
    union { __hip_bfloat16 b; ushort u; } cv;
    cv.b = __float2bfloat16(x);
    return cv.u;
}

__device__ __forceinline__ void gld16(const void* g, void* l) {
    __builtin_amdgcn_global_load_lds((const __attribute__((address_space(1))) void*)g,
                                     (__attribute__((address_space(3))) void*)l,
                                     16, 0, 0);
}

// ---------------------------------------------------------------------------
// fp32 weight [1024x1024] -> hi/lo bf16 split arrays
// ---------------------------------------------------------------------------
__global__ __launch_bounds__(256) void convert_w(
    const float* __restrict__ src, ushort* __restrict__ hi, ushort* __restrict__ lo)
{
    const int i = (blockIdx.x * 256 + threadIdx.x) * 8;
    const float4 f0 = *(const float4*)&src[i];
    const float4 f1 = *(const float4*)&src[i + 4];
    uint4 hv, lv;
    cvt8(f0, f1, hv, lv);
    *(uint4*)&hi[i] = hv;
    *(uint4*)&lo[i] = lv;
}

// ---------------------------------------------------------------------------
// Fused QKV GEMM (split-bf16 MFMA, fp32-accurate).
// Outputs: Qb bf16 [B*H][S][64] pre-scaled by QSCALE, Kb bf16 [B*H][S][64],
//          Vt bf16 [B*H][64][S] (transposed for PV B-operand reads).
// ---------------------------------------------------------------------------
__global__ __launch_bounds__(256) void qkv_gemm(
    const float* __restrict__ X,
    const ushort* __restrict__ Whi, const ushort* __restrict__ Wlo,
    const float* __restrict__ bq, const float* __restrict__ bk,
    const float* __restrict__ bv,
    ushort* __restrict__ Qb, ushort* __restrict__ Kb, ushort* __restrict__ Vt)
{
    __shared__ __align__(16) ushort Ahi[128 * 32];
    __shared__ __align__(16) ushort Alo[128 * 32];
    __shared__ __align__(16) ushort Bhi[128 * 32];
    __shared__ __align__(16) ushort Blo[128 * 32];

    const int tid = threadIdx.x;
    const int wave = tid >> 6;
    const int lane = tid & 63;
    const int lm = lane & 15;
    const int lq = lane >> 4;
    const int wy = wave >> 1;
    const int wx = wave & 1;
    const int m0 = blockIdx.x * 128;
    const int nbase = blockIdx.y * 128;

    const int ar = tid >> 1;
    const int ah_ = tid & 1;
    const float* ap = X + (size_t)(m0 + ar) * DIMSZ + ah_ * 16;
    const int wr0 = ar * 32 + (((ah_ * 2 + 0) ^ swz(ar & 15)) << 3);
    const int wr1 = ar * 32 + (((ah_ * 2 + 1) ^ swz(ar & 15)) << 3);

    const int c = tid & 3;
    const int r0 = tid >> 2;
    const int g = c ^ swz(r0 & 15);
    const ushort* gbh = Whi + (size_t)(nbase + r0) * DIMSZ + g * 8;
    const ushort* gbl = Wlo + (size_t)(nbase + r0) * DIMSZ + g * 8;
    ushort* lbh0 = &Bhi[wave * 512];
    ushort* lbh1 = &Bhi[2048 + wave * 512];
    ushort* lbl0 = &Blo[wave * 512];
    ushort* lbl1 = &Blo[2048 + wave * 512];

    const int fo = lm * 32 + (((lq ^ swz(lm)) & 3) << 3);
    int aofs[4], bofs[4];
#pragma unroll
    for (int i = 0; i < 4; ++i) {
        aofs[i] = (wy * 64 + i * 16) * 32 + fo;
        bofs[i] = (wx * 64 + i * 16) * 32 + fo;
    }

    f32x4 acc[4][4] = {};

    for (int k0 = 0; k0 < DIMSZ; k0 += 32) {
        const float4 f0 = *(const float4*)(ap + k0 + 0);
        const float4 f1 = *(const float4*)(ap + k0 + 4);
        const float4 f2 = *(const float4*)(ap + k0 + 8);
        const float4 f3 = *(const float4*)(ap + k0 + 12);

        __syncthreads();

        gld16(gbh + k0, lbh0);
        gld16(gbh + 64 * DIMSZ + k0, lbh1);
        gld16(gbl + k0, lbl0);
        gld16(gbl + 64 * DIMSZ + k0, lbl1);

        uint4 hv0, lv0, hv1, lv1;
        cvt8(f0, f1, hv0, lv0);
        cvt8(f2, f3, hv1, lv1);
        *(uint4*)&Ahi[wr0] = hv0;
        *(uint4*)&Ahi[wr1] = hv1;
        *(uint4*)&Alo[wr0] = lv0;
        *(uint4*)&Alo[wr1] = lv1;

        __syncthreads();

        bf16x8 ahf[4], alf[4], bhf[4], blf[4];
#pragma unroll
        for (int i = 0; i < 4; ++i) {
            ahf[i] = *(const bf16x8*)&Ahi[aofs[i]];
            alf[i] = *(const bf16x8*)&Alo[aofs[i]];
            bhf[i] = *(const bf16x8*)&Bhi[bofs[i]];
            blf[i] = *(const bf16x8*)&Blo[bofs[i]];
        }
#pragma unroll
        for (int i = 0; i < 4; ++i)
#pragma unroll
            for (int j = 0; j < 4; ++j) {
                acc[i][j] = __builtin_amdgcn_mfma_f32_16x16x32_bf16(ahf[i], bhf[j], acc[i][j], 0, 0, 0);
                acc[i][j] = __builtin_amdgcn_mfma_f32_16x16x32_bf16(ahf[i], blf[j], acc[i][j], 0, 0, 0);
                acc[i][j] = __builtin_amdgcn_mfma_f32_16x16x32_bf16(alf[i], bhf[j], acc[i][j], 0, 0, 0);
            }
    }

    // epilogue: C layout col=lm, row=lq*4+reg (verified by round-2 pass)
    const int mat = blockIdx.y >> 3;      // 0:Q 1:K 2:V (block-uniform)
    const float* bias = (mat == 0) ? bq : (mat == 1) ? bk : bv;
    const int nloc0 = (blockIdx.y & 7) * 128;

#pragma unroll
    for (int j = 0; j < 4; ++j) {
        const int nc = nloc0 + wx * 64 + j * 16 + lm;   // 0..1023
        const float bb = bias[nc];
        const int h = nc >> 6;
        const int d = nc & 63;
#pragma unroll
        for (int i = 0; i < 4; ++i) {
            const int mb = m0 + wy * 64 + i * 16 + lq * 4;
            const int b = mb >> 11;
            const int s = mb & (SEQ - 1);
            const int bh = b * NHEAD + h;
            if (mat == 2) {
                ushort4 pk;
                pk.x = f2bf(acc[i][j][0] + bb);
                pk.y = f2bf(acc[i][j][1] + bb);
                pk.z = f2bf(acc[i][j][2] + bb);
                pk.w = f2bf(acc[i][j][3] + bb);
                *(ushort4*)&Vt[((size_t)bh * HDIM + d) * SEQ + s] = pk;
            } else {
                ushort* dst = (mat == 0) ? Qb : Kb;
                const float sc = (mat == 0) ? QSCALE : 1.0f;
#pragma unroll
                for (int rr = 0; rr < 4; ++rr)
                    dst[((size_t)bh * SEQ + s + rr) * HDIM + d] = f2bf((acc[i][j][rr] + bb) * sc);
            }
        }
    }
}

// ---------------------------------------------------------------------------
// MFMA flash attention. Grid (SEQ/128, B*H), 256 thr = 4 waves.
// Wave w owns 32 query rows; K/V chunks of 64 double-buffered in LDS via
// global_load_lds + XOR chunk swizzle; softmax stats register-resident
// (shfl_xor over the 16-lane lm group); P via per-wave-private padded LDS.
// ---------------------------------------------------------------------------
__global__ __launch_bounds__(256) void flash_attn_mfma(
    const ushort* __restrict__ Qb, const ushort* __restrict__ Kb,
    const ushort* __restrict__ Vt, float* __restrict__ CTX)
{
    __shared__ __align__(16) ushort Ks[2][64 * 64];
    __shared__ __align__(16) ushort Vs[2][64 * 64];
    __shared__ __align__(16) ushort Ps[128 * 72];   // 144B rows: aligned + rotating

    const int tid = threadIdx.x;
    const int w = tid >> 6;
    const int l = tid & 63;
    const int lm = l & 15;
    const int lq = l >> 4;
    const int q0 = blockIdx.x * 128;
    const int bh = blockIdx.y;

    const ushort* Kg = Kb + (size_t)bh * SEQ * HDIM;
    const ushort* Vg = Vt + (size_t)bh * HDIM * SEQ;

    // staging: lane covers row base+(l>>3), slot l&7; slot s holds chunk s^(row&7)
    const int srow = w * 8 + (l >> 3);          // + p*32
    const int sc_ = (l & 7) ^ ((l >> 3) & 7);   // global chunk for this lane

    // Q fragments: register-resident for the whole kernel
    bf16x8 qf[2][2];
#pragma unroll
    for (int rt = 0; rt < 2; ++rt)
#pragma unroll
        for (int kt = 0; kt < 2; ++kt)
            qf[rt][kt] = *(const bf16x8*)&Qb[((size_t)bh * SEQ + q0 + w * 32 + rt * 16 + lm) * HDIM + kt * 32 + lq * 8];

    // LDS frag offsets for K/V tiles: row=t*16+lm, chunk kt*4+lq, swizzled slot
    int koff[4][2];
#pragma unroll
    for (int t = 0; t < 4; ++t)
#pragma unroll
        for (int kt = 0; kt < 2; ++kt) {
            const int row = t * 16 + lm;
            koff[t][kt] = row * 64 + (((kt * 4 + lq) ^ (row & 7)) << 3);
        }

    f32x4 o[2][4] = {};
    float m_[2][4], l_[2][4];
#pragma unroll
    for (int rt = 0; rt < 2; ++rt)
#pragma unroll
        for (int r = 0; r < 4; ++r) { m_[rt][r] = -1e30f; l_[rt][r] = 0.0f; }

    // stage chunk 0 into buf 0
    {
        ushort* kb = &Ks[0][0];
        ushort* vb = &Vs[0][0];
#pragma unroll
        for (int p = 0; p < 2; ++p) {
            const int row = p * 32 + srow;
            gld16(Kg + (size_t)row * HDIM + sc_ * 8, kb + (p * 32 + w * 8) * 64);
            gld16(Vg + (size_t)row * SEQ + sc_ * 8, vb + (p * 32 + w * 8) * 64);
        }
    }

    for (int ch = 0; ch < SEQ / 64; ++ch) {
        __syncthreads();   // buf[ch&1] staged (barrier drains vmcnt)

        if (ch + 1 < SEQ / 64) {   // prefetch next chunk into the other buffer
            const int kc = (ch + 1) * 64;
            ushort* kb = &Ks[(ch + 1) & 1][0];
            ushort* vb = &Vs[(ch + 1) & 1][0];
#pragma unroll
            for (int p = 0; p < 2; ++p) {
                const int row = p * 32 + srow;
                gld16(Kg + (size_t)(kc + row) * HDIM + sc_ * 8, kb + (p * 32 + w * 8) * 64);
                gld16(Vg + (size_t)row * SEQ + kc + sc_ * 8, vb + (p * 32 + w * 8) * 64);
            }
        }

        const ushort* kb = &Ks[ch & 1][0];
        const ushort* vb = &Vs[ch & 1][0];

        // S = Q K^T (exp2 domain, scale pre-folded into Q)
        f32x4 s[2][4] = {};
#pragma unroll
        for (int ct = 0; ct < 4; ++ct)
#pragma unroll
            for (int kt = 0; kt < 2; ++kt) {
                const bf16x8 kf = *(const bf16x8*)&kb[koff[ct][kt]];
#pragma unroll
                for (int rt = 0; rt < 2; ++rt)
                    s[rt][ct] = __builtin_amdgcn_mfma_f32_16x16x32_bf16(qf[rt][kt], kf, s[rt][ct], 0, 0, 0);
            }

        // online softmax, stats in registers (row = rt*16 + lq*4 + r)
#pragma unroll
        for (int rt = 0; rt < 2; ++rt) {
#pragma unroll
            for (int r = 0; r < 4; ++r) {
                float v = fmaxf(fmaxf(s[rt][0][r], s[rt][1][r]),
                                fmaxf(s[rt][2][r], s[rt][3][r]));
                v = fmaxf(v, __shfl_xor(v, 1, 64));
                v = fmaxf(v, __shfl_xor(v, 2, 64));
                v = fmaxf(v, __shfl_xor(v, 4, 64));
                v = fmaxf(v, __shfl_xor(v, 8, 64));
                const float mo = m_[rt][r];
                const float mn = fmaxf(mo, v);
                const float alpha = __builtin_amdgcn_exp2f(mo - mn);
                m_[rt][r] = mn;
                float ps = 0.0f;
#pragma unroll
                for (int ct = 0; ct < 4; ++ct) {
                    const float p = __builtin_amdgcn_exp2f(s[rt][ct][r] - mn);
                    Ps[(w * 32 + rt * 16 + lq * 4 + r) * 72 + ct * 16 + lm] = f2bf(p);
                    ps += p;
                }
                ps += __shfl_xor(ps, 1, 64);
                ps += __shfl_xor(ps, 2, 64);
                ps += __shfl_xor(ps, 4, 64);
                ps += __shfl_xor(ps, 8, 64);
                l_[rt][r] = l_[rt][r] * alpha + ps;
#pragma unroll
                for (int dt = 0; dt < 4; ++dt) o[rt][dt][r] *= alpha;
            }
        }

        // O += P V   (P A-frags from wave-private LDS; V B-frags swizzled)
#pragma unroll
        for (int kt2 = 0; kt2 < 2; ++kt2) {
            bf16x8 pf[2];
#pragma unroll
            for (int rt = 0; rt < 2; ++rt)
                pf[rt] = *(const bf16x8*)&Ps[(w * 32 + rt * 16 + lm) * 72 + kt2 * 32 + lq * 8];
#pragma unroll
            for (int dt = 0; dt < 4; ++dt) {
                const bf16x8 vf = *(const bf16x8*)&vb[koff[dt][kt2]];
#pragma unroll
                for (int rt = 0; rt < 2; ++rt)
                    o[rt][dt] = __builtin_amdgcn_mfma_f32_16x16x32_bf16(pf[rt], vf, o[rt][dt], 0, 0, 0);
            }
        }
    }

    const int b = bh >> 4;
    const int h = bh & 15;
#pragma unroll
    for (int rt = 0; rt < 2; ++rt)
#pragma unroll
        for (int r = 0; r < 4; ++r) {
            const float linv = 1.0f / l_[rt][r];
            const int srow_ = q0 + w * 32 + rt * 16 + lq * 4 + r;
            float* crow = &CTX[((size_t)b * SEQ + srow_) * DIMSZ + h * HDIM];
#pragma unroll
            for (int dt = 0; dt < 4; ++dt)
                crow[dt * 16 + lm] = o[rt][dt][r] * linv;
        }
}

// ---------------------------------------------------------------------------
// Output projection (split-bf16 MFMA, operands converted in-kernel).
// ---------------------------------------------------------------------------
__global__ __launch_bounds__(256) void oproj_gemm(
    const float* __restrict__ A, const float* __restrict__ W,
    const float* __restrict__ bias, float* __restrict__ out)
{
    __shared__ __align__(16) ushort Ahi[128 * 32];
    __shared__ __align__(16) ushort Alo[128 * 32];
    __shared__ __align__(16) ushort Bhi[128 * 32];
    __shared__ __align__(16) ushort Blo[128 * 32];

    const int tid = threadIdx.x;
    const int wave = tid >> 6;
    const int lane = tid & 63;
    const int lm = lane & 15;
    const int lq = lane >> 4;
    const int wy = wave >> 1;
    const int wx = wave & 1;
    const int m0 = blockIdx.x * 128;
    const int n0 = blockIdx.y * 128;

    const int ar = tid >> 1;
    const int ah_ = tid & 1;
    const float* ap = A + (size_t)(m0 + ar) * DIMSZ + ah_ * 16;
    const float* bp = W + (size_t)(n0 + ar) * DIMSZ + ah_ * 16;
    const int wr0 = ar * 32 + (((ah_ * 2 + 0) ^ swz(ar & 15)) << 3);
    const int wr1 = ar * 32 + (((ah_ * 2 + 1) ^ swz(ar & 15)) << 3);

    const int fo = lm * 32 + (((lq ^ swz(lm)) & 3) << 3);
    int aofs[4], bofs[4];
#pragma unroll
    for (int i = 0; i < 4; ++i) {
        aofs[i] = (wy * 64 + i * 16) * 32 + fo;
        bofs[i] = (wx * 64 + i * 16) * 32 + fo;
    }

    f32x4 acc[4][4] = {};

    for (int k0 = 0; k0 < DIMSZ; k0 += 32) {
        const float4 a0 = *(const float4*)(ap + k0 + 0);
        const float4 a1 = *(const float4*)(ap + k0 + 4);
        const float4 a2 = *(const float4*)(ap + k0 + 8);
        const float4 a3 = *(const float4*)(ap + k0 + 12);
        const float4 b0 = *(const float4*)(bp + k0 + 0);
        const float4 b1 = *(const float4*)(bp + k0 + 4);
        const float4 b2 = *(const float4*)(bp + k0 + 8);
        const float4 b3 = *(const float4*)(bp + k0 + 12);

        __syncthreads();

        uint4 hv, lv;
        cvt8(a0, a1, hv, lv); *(uint4*)&Ahi[wr0] = hv; *(uint4*)&Alo[wr0] = lv;
        cvt8(a2, a3, hv, lv); *(uint4*)&Ahi[wr1] = hv; *(uint4*)&Alo[wr1] = lv;
        cvt8(b0, b1, hv, lv); *(uint4*)&Bhi[wr0] = hv; *(uint4*)&Blo[wr0] = lv;
        cvt8(b2, b3, hv, lv); *(uint4*)&Bhi[wr1] = hv; *(uint4*)&Blo[wr1] = lv;

        __syncthreads();

        bf16x8 ahf[4], alf[4], bhf[4], blf[4];
#pragma unroll
        for (int i = 0; i < 4; ++i) {
            ahf[i] = *(const bf16x8*)&Ahi[aofs[i]];
            alf[i] = *(const bf16x8*)&Alo[aofs[i]];
            bhf[i] = *(const bf16x8*)&Bhi[bofs[i]];
            blf[i] = *(const bf16x8*)&Blo[bofs[i]];
        }
#pragma unroll
        for (int i = 0; i < 4; ++i)
#pragma unroll
            for (int j = 0; j < 4; ++j) {
                acc[i][j] = __builtin_amdgcn_mfma_f32_16x16x32_bf16(ahf[i], bhf[j], acc[i][j], 0, 0, 0);
                acc[i][j] = __builtin_amdgcn_mfma_f32_16x16x32_bf16(ahf[i], blf[j], acc[i][j], 0, 0, 0);
                acc[i][j] = __builtin_amdgcn_mfma_f32_16x16x32_bf16(alf[i], bhf[j], acc[i][j], 0, 0, 0);
            }
    }

#pragma unroll
    for (int j = 0; j < 4; ++j) {
        const int nc = n0 + wx * 64 + j * 16 + lm;
        const float bb = bias[nc];
#pragma unroll
        for (int i = 0; i < 4; ++i) {
            const int mb = m0 + wy * 64 + i * 16 + lq * 4;
#pragma unroll
            for (int rr = 0; rr < 4; ++rr)
                out[(size_t)(mb + rr) * DIMSZ + nc] = acc[i][j][rr] + bb;
        }
    }
}

// ---------------------------------------------------------------------------
extern "C" void kernel_launch(void* const* d_in, const int* in_sizes, int n_in,
                              void* d_out, int out_size, void* d_ws, size_t ws_size,
                              hipStream_t stream)
{
    const float* x  = (const float*)d_in[0];
    const float* Wq = (const float*)d_in[1];
    const float* bq = (const float*)d_in[2];
    const float* Wk = (const float*)d_in[3];
    const float* bk = (const float*)d_in[4];
    const float* Wv = (const float*)d_in[5];
    const float* bv = (const float*)d_in[6];
    const float* Wo = (const float*)d_in[7];
    const float* bo = (const float*)d_in[8];
    float* out = (float*)d_out;

    const size_t elems = (size_t)NROWS * DIMSZ;    // 4M
    ushort* Qb = (ushort*)d_ws;                    // 8MB
    ushort* Kb = Qb + elems;                       // 8MB
    ushort* Vt = Kb + elems;                       // 8MB
    float* CTX = (float*)(Vt + elems);             // 16MB fp32
    // W hi/lo converts overlay CTX (dead before flash_attn writes CTX)
    ushort* Whi = (ushort*)CTX;
    ushort* Wlo = Whi + 3 * (1 << 20);

    convert_w<<<512, 256, 0, stream>>>(Wq, Whi, Wlo);
    convert_w<<<512, 256, 0, stream>>>(Wk, Whi + (1 << 20), Wlo + (1 << 20));
    convert_w<<<512, 256, 0, stream>>>(Wv, Whi + 2 * (1 << 20), Wlo + 2 * (1 << 20));

    qkv_gemm<<<dim3(32, 24), 256, 0, stream>>>(x, Whi, Wlo, bq, bk, bv, Qb, Kb, Vt);

    flash_attn_mfma<<<dim3(SEQ / 128, BATCH * NHEAD), 256, 0, stream>>>(Qb, Kb, Vt, CTX);

    oproj_gemm<<<dim3(32, 8), 256, 0, stream>>>(CTX, Wo, bo, out);
}

// Round 4
// 274.765 us; speedup vs baseline: 4.0123x; 1.3125x over previous
//
#include <hip/hip_runtime.h>
#include <hip/hip_bf16.h>
#include <math.h>

#define DIMSZ 1024
#define NHEAD 16
#define HDIM 64
#define BATCH 2
#define SEQ 2048
#define NROWS (BATCH * SEQ)   // 4096

// softmax in exp2 domain: fold 1/sqrt(64) * log2(e) into Q at conversion
#define QSCALE 0.18033688011112042592f

typedef __attribute__((ext_vector_type(8))) short bf16x8;
typedef __attribute__((ext_vector_type(4))) float f32x4;

__device__ __forceinline__ int swz(int m) { return (m ^ (m >> 2)) & 3; }

__device__ __forceinline__ unsigned hipack(unsigned a, unsigned b) {
    return __builtin_amdgcn_perm(b, a, 0x07060302u);
}

// truncation split: hi = trunc-bf16(x), lo = trunc-bf16(x - hi)
__device__ __forceinline__ void cvt2(float x, float y, unsigned& h, unsigned& l) {
    unsigned ux = __float_as_uint(x), uy = __float_as_uint(y);
    h = hipack(ux, uy);
    float rx = x - __uint_as_float(ux & 0xFFFF0000u);
    float ry = y - __uint_as_float(uy & 0xFFFF0000u);
    l = hipack(__float_as_uint(rx), __float_as_uint(ry));
}

__device__ __forceinline__ void cvt8(const float4& f0, const float4& f1,
                                     uint4& hv, uint4& lv) {
    cvt2(f0.x, f0.y, hv.x, lv.x);
    cvt2(f0.z, f0.w, hv.y, lv.y);
    cvt2(f1.x, f1.y, hv.z, lv.z);
    cvt2(f1.z, f1.w, hv.w, lv.w);
}

__device__ __forceinline__ ushort f2bf(float x) {
    union { __hip_bfloat16 b; ushort u; } cv;
    cv.b = __float2bfloat16(x);
    return cv.u;
}

__device__ __forceinline__ void gld16(const void* g, void* l) {
    __builtin_amdgcn_global_load_lds((const __attribute__((address_space(1))) void*)g,
                                     (__attribute__((address_space(3))) void*)l,
                                     16, 0, 0);
}

// ---------------------------------------------------------------------------
// fp32 weight [1024x1024] -> hi/lo bf16 split arrays
// ---------------------------------------------------------------------------
__global__ __launch_bounds__(256) void convert_w(
    const float* __restrict__ src, ushort* __restrict__ hi, ushort* __restrict__ lo)
{
    const int i = (blockIdx.x * 256 + threadIdx.x) * 8;
    const float4 f0 = *(const float4*)&src[i];
    const float4 f1 = *(const float4*)&src[i + 4];
    uint4 hv, lv;
    cvt8(f0, f1, hv, lv);
    *(uint4*)&hi[i] = hv;
    *(uint4*)&lo[i] = lv;
}

// ---------------------------------------------------------------------------
// Fused QKV GEMM (split-bf16 MFMA).
// Qb bf16 [B*H][S][64] pre-scaled; Kb bf16 [B*H][S][64];
// Vt bf16 [B*H][64][S] transposed AND key-permuted within 32-blocks
// (position 8*lq+4*t+r holds key 16*t+4*lq+r) so flash PV B-frags are b128.
// V transpose goes through LDS (coalesced stores); LDS reused via smem union.
// ---------------------------------------------------------------------------
__global__ __launch_bounds__(256) void qkv_gemm(
    const float* __restrict__ X,
    const ushort* __restrict__ Whi, const ushort* __restrict__ Wlo,
    const float* __restrict__ bq, const float* __restrict__ bk,
    const float* __restrict__ bv,
    ushort* __restrict__ Qb, ushort* __restrict__ Kb, ushort* __restrict__ Vt)
{
    __shared__ __align__(16) ushort smem[17408];   // K-loop: 4x4096; epi: 2x64x136
    ushort* Ahi = smem;
    ushort* Alo = smem + 4096;
    ushort* Bhi = smem + 8192;
    ushort* Blo = smem + 12288;

    const int tid = threadIdx.x;
    const int wave = tid >> 6;
    const int lane = tid & 63;
    const int lm = lane & 15;
    const int lq = lane >> 4;
    const int wy = wave >> 1;
    const int wx = wave & 1;
    const int m0 = blockIdx.x * 128;
    const int nbase = blockIdx.y * 128;

    const int ar = tid >> 1;
    const int ah_ = tid & 1;
    const float* ap = X + (size_t)(m0 + ar) * DIMSZ + ah_ * 16;
    const int wr0 = ar * 32 + (((ah_ * 2 + 0) ^ swz(ar & 15)) << 3);
    const int wr1 = ar * 32 + (((ah_ * 2 + 1) ^ swz(ar & 15)) << 3);

    const int c = tid & 3;
    const int r0 = tid >> 2;
    const int g = c ^ swz(r0 & 15);
    const ushort* gbh = Whi + (size_t)(nbase + r0) * DIMSZ + g * 8;
    const ushort* gbl = Wlo + (size_t)(nbase + r0) * DIMSZ + g * 8;
    ushort* lbh0 = &Bhi[wave * 512];
    ushort* lbh1 = &Bhi[2048 + wave * 512];
    ushort* lbl0 = &Blo[wave * 512];
    ushort* lbl1 = &Blo[2048 + wave * 512];

    const int fo = lm * 32 + (((lq ^ swz(lm)) & 3) << 3);
    int aofs[4], bofs[4];
#pragma unroll
    for (int i = 0; i < 4; ++i) {
        aofs[i] = (wy * 64 + i * 16) * 32 + fo;
        bofs[i] = (wx * 64 + i * 16) * 32 + fo;
    }

    f32x4 acc[4][4] = {};

    for (int k0 = 0; k0 < DIMSZ; k0 += 32) {
        const float4 f0 = *(const float4*)(ap + k0 + 0);
        const float4 f1 = *(const float4*)(ap + k0 + 4);
        const float4 f2 = *(const float4*)(ap + k0 + 8);
        const float4 f3 = *(const float4*)(ap + k0 + 12);

        __syncthreads();

        gld16(gbh + k0, lbh0);
        gld16(gbh + 64 * DIMSZ + k0, lbh1);
        gld16(gbl + k0, lbl0);
        gld16(gbl + 64 * DIMSZ + k0, lbl1);

        uint4 hv0, lv0, hv1, lv1;
        cvt8(f0, f1, hv0, lv0);
        cvt8(f2, f3, hv1, lv1);
        *(uint4*)&Ahi[wr0] = hv0;
        *(uint4*)&Ahi[wr1] = hv1;
        *(uint4*)&Alo[wr0] = lv0;
        *(uint4*)&Alo[wr1] = lv1;

        __syncthreads();

        bf16x8 ahf[4], alf[4], bhf[4], blf[4];
#pragma unroll
        for (int i = 0; i < 4; ++i) {
            ahf[i] = *(const bf16x8*)&Ahi[aofs[i]];
            alf[i] = *(const bf16x8*)&Alo[aofs[i]];
            bhf[i] = *(const bf16x8*)&Bhi[bofs[i]];
            blf[i] = *(const bf16x8*)&Blo[bofs[i]];
        }
#pragma unroll
        for (int i = 0; i < 4; ++i)
#pragma unroll
            for (int j = 0; j < 4; ++j) {
                acc[i][j] = __builtin_amdgcn_mfma_f32_16x16x32_bf16(ahf[i], bhf[j], acc[i][j], 0, 0, 0);
                acc[i][j] = __builtin_amdgcn_mfma_f32_16x16x32_bf16(ahf[i], blf[j], acc[i][j], 0, 0, 0);
                acc[i][j] = __builtin_amdgcn_mfma_f32_16x16x32_bf16(alf[i], bhf[j], acc[i][j], 0, 0, 0);
            }
    }

    const int mat = blockIdx.y >> 3;      // 0:Q 1:K 2:V (block-uniform)
    const float* bias = (mat == 0) ? bq : (mat == 1) ? bk : bv;
    const int nloc0 = (blockIdx.y & 7) * 128;
    const int b = m0 >> 11;
    const int s0 = m0 & (SEQ - 1);

    if (mat == 2) {
        // ---- V: bias + bf16 + transpose via LDS, key-permuted, coalesced out
        __syncthreads();   // last iteration's frag reads complete
#pragma unroll
        for (int j = 0; j < 4; ++j) {
            const int nc = nloc0 + wx * 64 + j * 16 + lm;
            const float bb = bias[nc];
            const int d = j * 16 + lm;    // nc & 63
#pragma unroll
            for (int i = 0; i < 4; ++i) {
                // permuted position within 32-block: 8*lq + 4*(i&1) + rr
                const int ss = wy * 64 + (i >> 1) * 32 + lq * 8 + (i & 1) * 4;
                ushort4 pk;
                pk.x = f2bf(acc[i][j][0] + bb);
                pk.y = f2bf(acc[i][j][1] + bb);
                pk.z = f2bf(acc[i][j][2] + bb);
                pk.w = f2bf(acc[i][j][3] + bb);
                *(ushort4*)&smem[(wx * 64 + d) * 136 + ss] = pk;
            }
        }
        __syncthreads();
#pragma unroll
        for (int p = 0; p < 8; ++p) {
            const int idx = p * 256 + tid;
            const int row = idx >> 4;          // 0..127  (hh*64 + d)
            const int hh = row >> 6;
            const int d = row & 63;
            const int sseg = (idx & 15) * 8;
            const uint4 v = *(const uint4*)&smem[row * 136 + sseg];
            const int hg = (nloc0 >> 6) + hh;
            *(uint4*)&Vt[((size_t)(b * NHEAD + hg) * HDIM + d) * SEQ + s0 + sseg] = v;
        }
    } else {
        ushort* dst = (mat == 0) ? Qb : Kb;
        const float sc = (mat == 0) ? QSCALE : 1.0f;
#pragma unroll
        for (int j = 0; j < 4; ++j) {
            const int nc = nloc0 + wx * 64 + j * 16 + lm;
            const float bb = bias[nc];
            const int h = nc >> 6;
            const int d = nc & 63;
#pragma unroll
            for (int i = 0; i < 4; ++i) {
                const int mb = m0 + wy * 64 + i * 16 + lq * 4;
                const int s = mb & (SEQ - 1);
                const int bh = b * NHEAD + h;
#pragma unroll
                for (int rr = 0; rr < 4; ++rr)
                    dst[((size_t)bh * SEQ + s + rr) * HDIM + d] = f2bf((acc[i][j][rr] + bb) * sc);
            }
        }
    }
}

// ---------------------------------------------------------------------------
// MFMA flash attention, S^T formulation.
// st = mfma(K-frag, Q-frag) -> lane col = query: P stays in registers
// (exp2 -> bf16 pack -> PV A-frag). Fixed-shift softmax (scores bounded,
// exp2 domain |s| < ~6): no max tracking, no rescale; l = reg sum + 2 shfl.
// V global layout is key-permuted so PV B-frags are straight b128 reads.
// ---------------------------------------------------------------------------
__global__ __launch_bounds__(256) void flash_attn_mfma(
    const ushort* __restrict__ Qb, const ushort* __restrict__ Kb,
    const ushort* __restrict__ Vt,
    ushort* __restrict__ CTXhi, ushort* __restrict__ CTXlo)
{
    __shared__ __align__(16) ushort Ks[2][4096];
    __shared__ __align__(16) ushort Vs[2][4096];

    const int tid = threadIdx.x;
    const int w = tid >> 6;
    const int l = tid & 63;
    const int lm = l & 15;
    const int lq = l >> 4;
    const int q0 = blockIdx.x * 128;
    const int bh = blockIdx.y;

    const ushort* Kg = Kb + (size_t)bh * SEQ * HDIM;
    const ushort* Vg = Vt + (size_t)bh * HDIM * SEQ;

    const int srow = w * 8 + (l >> 3);
    const int sc_ = (l & 7) ^ ((l >> 3) & 7);

    // Q B-frags, register-resident
    bf16x8 qf[2][2];
#pragma unroll
    for (int rt = 0; rt < 2; ++rt)
#pragma unroll
        for (int kt = 0; kt < 2; ++kt)
            qf[rt][kt] = *(const bf16x8*)&Qb[((size_t)bh * SEQ + q0 + w * 32 + rt * 16 + lm) * HDIM + kt * 32 + lq * 8];

    // frag offsets (shared by K and V tiles): row t*16+lm, chunk kt*4+lq, XOR swizzle
    int koff[4][2];
#pragma unroll
    for (int t = 0; t < 4; ++t)
#pragma unroll
        for (int kt = 0; kt < 2; ++kt)
            koff[t][kt] = (t * 16 + lm) * 64 + (((kt * 4 + lq) ^ (lm & 7)) << 3);

    f32x4 o[2][4] = {};
    float l_[2] = {0.0f, 0.0f};

    {
        ushort* kb = &Ks[0][0];
        ushort* vb = &Vs[0][0];
#pragma unroll
        for (int p = 0; p < 2; ++p) {
            const int row = p * 32 + srow;
            gld16(Kg + (size_t)row * HDIM + sc_ * 8, kb + (p * 32 + w * 8) * 64);
            gld16(Vg + (size_t)row * SEQ + sc_ * 8, vb + (p * 32 + w * 8) * 64);
        }
    }

    for (int ch = 0; ch < SEQ / 64; ++ch) {
        __syncthreads();   // buf[ch&1] staged (barrier drains vmcnt)

        if (ch + 1 < SEQ / 64) {
            const int kc = (ch + 1) * 64;
            ushort* kb = &Ks[(ch + 1) & 1][0];
            ushort* vb = &Vs[(ch + 1) & 1][0];
#pragma unroll
            for (int p = 0; p < 2; ++p) {
                const int row = p * 32 + srow;
                gld16(Kg + (size_t)(kc + row) * HDIM + sc_ * 8, kb + (p * 32 + w * 8) * 64);
                gld16(Vg + (size_t)row * SEQ + kc + sc_ * 8, vb + (p * 32 + w * 8) * 64);
            }
        }

        const ushort* kb = &Ks[ch & 1][0];
        const ushort* vb = &Vs[ch & 1][0];

        // S^T = K Q^T: lane col = query(lm), rows = keys(ct*16 + lq*4 + r)
        f32x4 st[2][4] = {};
#pragma unroll
        for (int ct = 0; ct < 4; ++ct)
#pragma unroll
            for (int kt = 0; kt < 2; ++kt) {
                const bf16x8 kf = *(const bf16x8*)&kb[koff[ct][kt]];
#pragma unroll
                for (int rt = 0; rt < 2; ++rt)
                    st[rt][ct] = __builtin_amdgcn_mfma_f32_16x16x32_bf16(kf, qf[rt][kt], st[rt][ct], 0, 0, 0);
            }

        // p = exp2(s) (fixed shift); l += rowsum (reduce over quads)
#pragma unroll
        for (int rt = 0; rt < 2; ++rt) {
            float ls = 0.0f;
#pragma unroll
            for (int ct = 0; ct < 4; ++ct)
#pragma unroll
                for (int r = 0; r < 4; ++r) {
                    const float p = __builtin_amdgcn_exp2f(st[rt][ct][r]);
                    st[rt][ct][r] = p;
                    ls += p;
                }
            ls += __shfl_xor(ls, 16, 64);
            ls += __shfl_xor(ls, 32, 64);
            l_[rt] += ls;
        }

        // pack P -> A-frags: slot j=4t+r of lane(lm,lq) holds key 32kt2+16t+4lq+r
        bf16x8 pf[2][2];
#pragma unroll
        for (int rt = 0; rt < 2; ++rt)
#pragma unroll
            for (int kt2 = 0; kt2 < 2; ++kt2) {
                union { bf16x8 v; ushort u[8]; } pk;
#pragma unroll
                for (int t = 0; t < 2; ++t)
#pragma unroll
                    for (int r = 0; r < 4; ++r)
                        pk.u[t * 4 + r] = f2bf(st[rt][kt2 * 2 + t][r]);
                pf[rt][kt2] = pk.v;
            }

        // O += P V (V global layout pre-permuted to match A-frag key order)
#pragma unroll
        for (int dt = 0; dt < 4; ++dt)
#pragma unroll
            for (int kt2 = 0; kt2 < 2; ++kt2) {
                const bf16x8 vf = *(const bf16x8*)&vb[koff[dt][kt2]];
#pragma unroll
                for (int rt = 0; rt < 2; ++rt)
                    o[rt][dt] = __builtin_amdgcn_mfma_f32_16x16x32_bf16(pf[rt][kt2], vf, o[rt][dt], 0, 0, 0);
            }
    }

    // epilogue: normalize + split-bf16 store of CTX
    const int b = bh >> 4;
    const int h = bh & 15;
#pragma unroll
    for (int rt = 0; rt < 2; ++rt) {
        const float linv_me = 1.0f / l_[rt];   // for query q0+w*32+rt*16+lm
#pragma unroll
        for (int r = 0; r < 4; ++r) {
            const float lr = __shfl(linv_me, lq * 4 + r, 64);
            const int srow_ = q0 + w * 32 + rt * 16 + lq * 4 + r;
            const size_t base = ((size_t)b * SEQ + srow_) * DIMSZ + h * HDIM;
#pragma unroll
            for (int dt = 0; dt < 4; ++dt) {
                const float v = o[rt][dt][r] * lr;
                const unsigned uv = __float_as_uint(v);
                CTXhi[base + dt * 16 + lm] = (ushort)(uv >> 16);
                const float res = v - __uint_as_float(uv & 0xFFFF0000u);
                CTXlo[base + dt * 16 + lm] = (ushort)(__float_as_uint(res) >> 16);
            }
        }
    }
}

// ---------------------------------------------------------------------------
// Output projection: all operands pre-split bf16, pure global_load_lds
// staging. 64x128 tiles -> 512 blocks (2/CU).
// ---------------------------------------------------------------------------
__global__ __launch_bounds__(256) void oproj_gemm(
    const ushort* __restrict__ Ahi_g, const ushort* __restrict__ Alo_g,
    const ushort* __restrict__ Bhi_g, const ushort* __restrict__ Blo_g,
    const float* __restrict__ bias, float* __restrict__ out)
{
    __shared__ __align__(16) ushort Ah[64 * 32], Al[64 * 32];
    __shared__ __align__(16) ushort Bh[128 * 32], Bl[128 * 32];

    const int tid = threadIdx.x;
    const int wave = tid >> 6;
    const int lane = tid & 63;
    const int lm = lane & 15;
    const int lq = lane >> 4;
    const int wy = wave >> 1;
    const int wx = wave & 1;
    const int m0 = blockIdx.x * 64;
    const int n0 = blockIdx.y * 128;

    const int c = tid & 3;
    const int r0 = tid >> 2;
    const int g = c ^ swz(r0 & 15);
    const ushort* gah = Ahi_g + (size_t)(m0 + r0) * DIMSZ + g * 8;
    const ushort* gal = Alo_g + (size_t)(m0 + r0) * DIMSZ + g * 8;
    const ushort* gbh = Bhi_g + (size_t)(n0 + r0) * DIMSZ + g * 8;
    const ushort* gbl = Blo_g + (size_t)(n0 + r0) * DIMSZ + g * 8;
    ushort* lah  = &Ah[wave * 512];
    ushort* lal  = &Al[wave * 512];
    ushort* lbh0 = &Bh[wave * 512];
    ushort* lbh1 = &Bh[2048 + wave * 512];
    ushort* lbl0 = &Bl[wave * 512];
    ushort* lbl1 = &Bl[2048 + wave * 512];

    const int fo = lm * 32 + (((lq ^ swz(lm)) & 3) << 3);
    int aofs[2], bofs[4];
#pragma unroll
    for (int i = 0; i < 2; ++i) aofs[i] = (wy * 32 + i * 16) * 32 + fo;
#pragma unroll
    for (int j = 0; j < 4; ++j) bofs[j] = (wx * 64 + j * 16) * 32 + fo;

    f32x4 acc[2][4] = {};

    for (int k0 = 0; k0 < DIMSZ; k0 += 32) {
        __syncthreads();

        gld16(gah + k0, lah);
        gld16(gal + k0, lal);
        gld16(gbh + k0, lbh0);
        gld16(gbh + 64 * DIMSZ + k0, lbh1);
        gld16(gbl + k0, lbl0);
        gld16(gbl + 64 * DIMSZ + k0, lbl1);

        __syncthreads();

        bf16x8 ahf[2], alf[2], bhf[4], blf[4];
#pragma unroll
        for (int i = 0; i < 2; ++i) {
            ahf[i] = *(const bf16x8*)&Ah[aofs[i]];
            alf[i] = *(const bf16x8*)&Al[aofs[i]];
        }
#pragma unroll
        for (int j = 0; j < 4; ++j) {
            bhf[j] = *(const bf16x8*)&Bh[bofs[j]];
            blf[j] = *(const bf16x8*)&Bl[bofs[j]];
        }
#pragma unroll
        for (int i = 0; i < 2; ++i)
#pragma unroll
            for (int j = 0; j < 4; ++j) {
                acc[i][j] = __builtin_amdgcn_mfma_f32_16x16x32_bf16(ahf[i], bhf[j], acc[i][j], 0, 0, 0);
                acc[i][j] = __builtin_amdgcn_mfma_f32_16x16x32_bf16(ahf[i], blf[j], acc[i][j], 0, 0, 0);
                acc[i][j] = __builtin_amdgcn_mfma_f32_16x16x32_bf16(alf[i], bhf[j], acc[i][j], 0, 0, 0);
            }
    }

#pragma unroll
    for (int j = 0; j < 4; ++j) {
        const int nc = n0 + wx * 64 + j * 16 + lm;
        const float bb = bias[nc];
#pragma unroll
        for (int i = 0; i < 2; ++i) {
            const int mb = m0 + wy * 32 + i * 16 + lq * 4;
#pragma unroll
            for (int rr = 0; rr < 4; ++rr)
                out[(size_t)(mb + rr) * DIMSZ + nc] = acc[i][j][rr] + bb;
        }
    }
}

// ---------------------------------------------------------------------------
extern "C" void kernel_launch(void* const* d_in, const int* in_sizes, int n_in,
                              void* d_out, int out_size, void* d_ws, size_t ws_size,
                              hipStream_t stream)
{
    const float* x  = (const float*)d_in[0];
    const float* Wq = (const float*)d_in[1];
    const float* bq = (const float*)d_in[2];
    const float* Wk = (const float*)d_in[3];
    const float* bk = (const float*)d_in[4];
    const float* Wv = (const float*)d_in[5];
    const float* bv = (const float*)d_in[6];
    const float* Wo = (const float*)d_in[7];
    const float* bo = (const float*)d_in[8];
    float* out = (float*)d_out;

    const size_t elems = (size_t)NROWS * DIMSZ;   // 4M
    ushort* Qb    = (ushort*)d_ws;                // 8MB
    ushort* Kb    = Qb + elems;                   // 8MB
    ushort* Vt    = Kb + elems;                   // 8MB
    ushort* CTXhi = Vt + elems;                   // 8MB
    ushort* CTXlo = CTXhi + elems;                // 8MB
    ushort* Whi   = CTXlo + elems;                // 6MB (3M ushorts)
    ushort* Wlo   = Whi + 3 * (1 << 20);          // 6MB
    ushort* Wohi  = Wlo + 3 * (1 << 20);          // 2MB
    ushort* Wolo  = Wohi + (1 << 20);             // 2MB  (total 56MB)

    convert_w<<<512, 256, 0, stream>>>(Wq, Whi, Wlo);
    convert_w<<<512, 256, 0, stream>>>(Wk, Whi + (1 << 20), Wlo + (1 << 20));
    convert_w<<<512, 256, 0, stream>>>(Wv, Whi + 2 * (1 << 20), Wlo + 2 * (1 << 20));
    convert_w<<<512, 256, 0, stream>>>(Wo, Wohi, Wolo);

    qkv_gemm<<<dim3(32, 24), 256, 0, stream>>>(x, Whi, Wlo, bq, bk, bv, Qb, Kb, Vt);

    flash_attn_mfma<<<dim3(SEQ / 128, BATCH * NHEAD), 256, 0, stream>>>(Qb, Kb, Vt, CTXhi, CTXlo);

    oproj_gemm<<<dim3(64, 8), 256, 0, stream>>>(CTXhi, CTXlo, Wohi, Wolo, bo, out);
}

// Round 5
// 268.375 us; speedup vs baseline: 4.1078x; 1.0238x over previous
//
#include <hip/hip_runtime.h>
#include <hip/hip_bf16.h>
#include <math.h>

#define DIMSZ 1024
#define NHEAD 16
#define HDIM 64
#define BATCH 2
#define SEQ 2048
#define NROWS (BATCH * SEQ)   // 4096

// softmax in exp2 domain: fold 1/sqrt(64) * log2(e) into Q at conversion
#define QSCALE 0.18033688011112042592f

typedef __attribute__((ext_vector_type(8))) short bf16x8;
typedef __attribute__((ext_vector_type(4))) float f32x4;

__device__ __forceinline__ int swz(int m) { return (m ^ (m >> 2)) & 3; }

__device__ __forceinline__ unsigned hipack(unsigned a, unsigned b) {
    return __builtin_amdgcn_perm(b, a, 0x07060302u);
}

// truncation split: hi = trunc-bf16(x), lo = trunc-bf16(x - hi)
__device__ __forceinline__ void cvt2(float x, float y, unsigned& h, unsigned& l) {
    unsigned ux = __float_as_uint(x), uy = __float_as_uint(y);
    h = hipack(ux, uy);
    float rx = x - __uint_as_float(ux & 0xFFFF0000u);
    float ry = y - __uint_as_float(uy & 0xFFFF0000u);
    l = hipack(__float_as_uint(rx), __float_as_uint(ry));
}

__device__ __forceinline__ void cvt8(const float4& f0, const float4& f1,
                                     uint4& hv, uint4& lv) {
    cvt2(f0.x, f0.y, hv.x, lv.x);
    cvt2(f0.z, f0.w, hv.y, lv.y);
    cvt2(f1.x, f1.y, hv.z, lv.z);
    cvt2(f1.z, f1.w, hv.w, lv.w);
}

__device__ __forceinline__ ushort f2bf(float x) {
    union { __hip_bfloat16 b; ushort u; } cv;
    cv.b = __float2bfloat16(x);
    return cv.u;
}

__device__ __forceinline__ void gld16(const void* g, void* l) {
    __builtin_amdgcn_global_load_lds((const __attribute__((address_space(1))) void*)g,
                                     (__attribute__((address_space(3))) void*)l,
                                     16, 0, 0);
}

// ---------------------------------------------------------------------------
// fp32 matrix -> hi/lo bf16 split planes (grid scales with element count)
// ---------------------------------------------------------------------------
__global__ __launch_bounds__(256) void convert_w(
    const float* __restrict__ src, ushort* __restrict__ hi, ushort* __restrict__ lo)
{
    const int i = (blockIdx.x * 256 + threadIdx.x) * 8;
    const float4 f0 = *(const float4*)&src[i];
    const float4 f1 = *(const float4*)&src[i + 4];
    uint4 hv, lv;
    cvt8(f0, f1, hv, lv);
    *(uint4*)&hi[i] = hv;
    *(uint4*)&lo[i] = lv;
}

// ---------------------------------------------------------------------------
// Fused QKV GEMM (split-bf16 MFMA), pure-gld16 double-buffered K-loop.
// All operands pre-split bf16 (Xhi/Xlo, Whi/Wlo). Prefetch of k-tile k+1 is
// issued right after the barrier releasing tile k, so the vmcnt(0) drain at
// the next barrier waits on loads that had a full iteration in flight.
// Outputs: Qb [B*H][S][64] bf16 pre-scaled; Kb same; Vt [B*H][64][S]
// key-permuted (flash PV A-frag order) via LDS-transposed coalesced stores.
// ---------------------------------------------------------------------------
__global__ __launch_bounds__(256) void qkv_gemm(
    const ushort* __restrict__ Xhi, const ushort* __restrict__ Xlo,
    const ushort* __restrict__ Whi, const ushort* __restrict__ Wlo,
    const float* __restrict__ bq, const float* __restrict__ bk,
    const float* __restrict__ bv,
    ushort* __restrict__ Qb, ushort* __restrict__ Kb, ushort* __restrict__ Vt)
{
    // per buffer: Ah[4096] Al[4096] Bh[4096] Bl[4096] ushorts = 32KB; x2 = 64KB
    __shared__ __align__(16) ushort smem[2][16384];

    const int tid = threadIdx.x;
    const int wave = tid >> 6;
    const int lane = tid & 63;
    const int lm = lane & 15;
    const int lq = lane >> 4;
    const int wy = wave >> 1;
    const int wx = wave & 1;
    const int m0 = blockIdx.x * 128;
    const int nbase = blockIdx.y * 128;

    // staging map: thread t -> row r0 = t>>2 (and r0+64), LDS slot c = t&3,
    // global chunk g = c ^ swz(r0&15)  (slot s of row r holds chunk s^swz(r&15))
    const int c = tid & 3;
    const int r0 = tid >> 2;
    const int g = c ^ swz(r0 & 15);
    const ushort* gah = Xhi + (size_t)(m0 + r0) * DIMSZ + g * 8;
    const ushort* gal = Xlo + (size_t)(m0 + r0) * DIMSZ + g * 8;
    const ushort* gbh = Whi + (size_t)(nbase + r0) * DIMSZ + g * 8;
    const ushort* gbl = Wlo + (size_t)(nbase + r0) * DIMSZ + g * 8;
    const int wofs = wave * 512;   // 64 lanes x 16B within a gld16 call

    // frag read offsets: lane gets k-chunk lq of its row (XOR-swizzle inverted)
    const int fo = lm * 32 + (((lq ^ swz(lm)) & 3) << 3);
    int aofs[4], bofs[4];
#pragma unroll
    for (int i = 0; i < 4; ++i) {
        aofs[i] = (wy * 64 + i * 16) * 32 + fo;
        bofs[i] = (wx * 64 + i * 16) * 32 + fo;
    }

    f32x4 acc[4][4] = {};

    // stage k-tile 0 into buffer 0
    {
        ushort* b0 = &smem[0][0];
        gld16(gah, b0 + wofs);                  gld16(gah + 64 * DIMSZ, b0 + 2048 + wofs);
        gld16(gal, b0 + 4096 + wofs);           gld16(gal + 64 * DIMSZ, b0 + 4096 + 2048 + wofs);
        gld16(gbh, b0 + 8192 + wofs);           gld16(gbh + 64 * DIMSZ, b0 + 8192 + 2048 + wofs);
        gld16(gbl, b0 + 12288 + wofs);          gld16(gbl + 64 * DIMSZ, b0 + 12288 + 2048 + wofs);
    }

    for (int kk = 0; kk < 32; ++kk) {
        __syncthreads();   // buffer kk&1 staged (prefetch had a full iter in flight)

        if (kk + 1 < 32) {
            const int k0 = (kk + 1) * 32;
            ushort* nb = &smem[(kk + 1) & 1][0];
            gld16(gah + k0, nb + wofs);                  gld16(gah + 64 * DIMSZ + k0, nb + 2048 + wofs);
            gld16(gal + k0, nb + 4096 + wofs);           gld16(gal + 64 * DIMSZ + k0, nb + 4096 + 2048 + wofs);
            gld16(gbh + k0, nb + 8192 + wofs);           gld16(gbh + 64 * DIMSZ + k0, nb + 8192 + 2048 + wofs);
            gld16(gbl + k0, nb + 12288 + wofs);          gld16(gbl + 64 * DIMSZ + k0, nb + 12288 + 2048 + wofs);
        }

        const ushort* Ah = &smem[kk & 1][0];
        const ushort* Al = Ah + 4096;
        const ushort* Bh = Ah + 8192;
        const ushort* Bl = Ah + 12288;

        bf16x8 ahf[4], alf[4], bhf[4], blf[4];
#pragma unroll
        for (int i = 0; i < 4; ++i) {
            ahf[i] = *(const bf16x8*)&Ah[aofs[i]];
            alf[i] = *(const bf16x8*)&Al[aofs[i]];
            bhf[i] = *(const bf16x8*)&Bh[bofs[i]];
            blf[i] = *(const bf16x8*)&Bl[bofs[i]];
        }
#pragma unroll
        for (int i = 0; i < 4; ++i)
#pragma unroll
            for (int j = 0; j < 4; ++j) {
                acc[i][j] = __builtin_amdgcn_mfma_f32_16x16x32_bf16(ahf[i], bhf[j], acc[i][j], 0, 0, 0);
                acc[i][j] = __builtin_amdgcn_mfma_f32_16x16x32_bf16(ahf[i], blf[j], acc[i][j], 0, 0, 0);
                acc[i][j] = __builtin_amdgcn_mfma_f32_16x16x32_bf16(alf[i], bhf[j], acc[i][j], 0, 0, 0);
            }
    }

    const int mat = blockIdx.y >> 3;      // 0:Q 1:K 2:V (block-uniform)
    const float* bias = (mat == 0) ? bq : (mat == 1) ? bk : bv;
    const int nloc0 = (blockIdx.y & 7) * 128;
    const int b = m0 >> 11;
    const int s0 = m0 & (SEQ - 1);
    ushort* sf = &smem[0][0];             // flat reuse for V transpose (needs 17408)

    if (mat == 2) {
        __syncthreads();   // all frag reads done before smem reuse
#pragma unroll
        for (int j = 0; j < 4; ++j) {
            const int nc = nloc0 + wx * 64 + j * 16 + lm;
            const float bb = bias[nc];
            const int d = j * 16 + lm;
#pragma unroll
            for (int i = 0; i < 4; ++i) {
                // permuted position within 32-block: 8*lq + 4*(i&1) + rr
                const int ss = wy * 64 + (i >> 1) * 32 + lq * 8 + (i & 1) * 4;
                ushort4 pk;
                pk.x = f2bf(acc[i][j][0] + bb);
                pk.y = f2bf(acc[i][j][1] + bb);
                pk.z = f2bf(acc[i][j][2] + bb);
                pk.w = f2bf(acc[i][j][3] + bb);
                *(ushort4*)&sf[(wx * 64 + d) * 136 + ss] = pk;
            }
        }
        __syncthreads();
#pragma unroll
        for (int p = 0; p < 8; ++p) {
            const int idx = p * 256 + tid;
            const int row = idx >> 4;          // hh*64 + d
            const int hh = row >> 6;
            const int d = row & 63;
            const int sseg = (idx & 15) * 8;
            const uint4 v = *(const uint4*)&sf[row * 136 + sseg];
            const int hg = (nloc0 >> 6) + hh;
            *(uint4*)&Vt[((size_t)(b * NHEAD + hg) * HDIM + d) * SEQ + s0 + sseg] = v;
        }
    } else {
        ushort* dst = (mat == 0) ? Qb : Kb;
        const float sc = (mat == 0) ? QSCALE : 1.0f;
#pragma unroll
        for (int j = 0; j < 4; ++j) {
            const int nc = nloc0 + wx * 64 + j * 16 + lm;
            const float bb = bias[nc];
            const int h = nc >> 6;
            const int d = nc & 63;
#pragma unroll
            for (int i = 0; i < 4; ++i) {
                const int mb = m0 + wy * 64 + i * 16 + lq * 4;
                const int s = mb & (SEQ - 1);
                const int bh = b * NHEAD + h;
#pragma unroll
                for (int rr = 0; rr < 4; ++rr)
                    dst[((size_t)bh * SEQ + s + rr) * HDIM + d] = f2bf((acc[i][j][rr] + bb) * sc);
            }
        }
    }
}

// ---------------------------------------------------------------------------
// MFMA flash attention, S^T formulation (unchanged from round 4).
// ---------------------------------------------------------------------------
__global__ __launch_bounds__(256) void flash_attn_mfma(
    const ushort* __restrict__ Qb, const ushort* __restrict__ Kb,
    const ushort* __restrict__ Vt,
    ushort* __restrict__ CTXhi, ushort* __restrict__ CTXlo)
{
    __shared__ __align__(16) ushort Ks[2][4096];
    __shared__ __align__(16) ushort Vs[2][4096];

    const int tid = threadIdx.x;
    const int w = tid >> 6;
    const int l = tid & 63;
    const int lm = l & 15;
    const int lq = l >> 4;
    const int q0 = blockIdx.x * 128;
    const int bh = blockIdx.y;

    const ushort* Kg = Kb + (size_t)bh * SEQ * HDIM;
    const ushort* Vg = Vt + (size_t)bh * HDIM * SEQ;

    const int srow = w * 8 + (l >> 3);
    const int sc_ = (l & 7) ^ ((l >> 3) & 7);

    bf16x8 qf[2][2];
#pragma unroll
    for (int rt = 0; rt < 2; ++rt)
#pragma unroll
        for (int kt = 0; kt < 2; ++kt)
            qf[rt][kt] = *(const bf16x8*)&Qb[((size_t)bh * SEQ + q0 + w * 32 + rt * 16 + lm) * HDIM + kt * 32 + lq * 8];

    int koff[4][2];
#pragma unroll
    for (int t = 0; t < 4; ++t)
#pragma unroll
        for (int kt = 0; kt < 2; ++kt)
            koff[t][kt] = (t * 16 + lm) * 64 + (((kt * 4 + lq) ^ (lm & 7)) << 3);

    f32x4 o[2][4] = {};
    float l_[2] = {0.0f, 0.0f};

    {
        ushort* kb = &Ks[0][0];
        ushort* vb = &Vs[0][0];
#pragma unroll
        for (int p = 0; p < 2; ++p) {
            const int row = p * 32 + srow;
            gld16(Kg + (size_t)row * HDIM + sc_ * 8, kb + (p * 32 + w * 8) * 64);
            gld16(Vg + (size_t)row * SEQ + sc_ * 8, vb + (p * 32 + w * 8) * 64);
        }
    }

    for (int ch = 0; ch < SEQ / 64; ++ch) {
        __syncthreads();

        if (ch + 1 < SEQ / 64) {
            const int kc = (ch + 1) * 64;
            ushort* kb = &Ks[(ch + 1) & 1][0];
            ushort* vb = &Vs[(ch + 1) & 1][0];
#pragma unroll
            for (int p = 0; p < 2; ++p) {
                const int row = p * 32 + srow;
                gld16(Kg + (size_t)(kc + row) * HDIM + sc_ * 8, kb + (p * 32 + w * 8) * 64);
                gld16(Vg + (size_t)row * SEQ + kc + sc_ * 8, vb + (p * 32 + w * 8) * 64);
            }
        }

        const ushort* kb = &Ks[ch & 1][0];
        const ushort* vb = &Vs[ch & 1][0];

        f32x4 st[2][4] = {};
#pragma unroll
        for (int ct = 0; ct < 4; ++ct)
#pragma unroll
            for (int kt = 0; kt < 2; ++kt) {
                const bf16x8 kf = *(const bf16x8*)&kb[koff[ct][kt]];
#pragma unroll
                for (int rt = 0; rt < 2; ++rt)
                    st[rt][ct] = __builtin_amdgcn_mfma_f32_16x16x32_bf16(kf, qf[rt][kt], st[rt][ct], 0, 0, 0);
            }

#pragma unroll
        for (int rt = 0; rt < 2; ++rt) {
            float ls = 0.0f;
#pragma unroll
            for (int ct = 0; ct < 4; ++ct)
#pragma unroll
                for (int r = 0; r < 4; ++r) {
                    const float p = __builtin_amdgcn_exp2f(st[rt][ct][r]);
                    st[rt][ct][r] = p;
                    ls += p;
                }
            ls += __shfl_xor(ls, 16, 64);
            ls += __shfl_xor(ls, 32, 64);
            l_[rt] += ls;
        }

        bf16x8 pf[2][2];
#pragma unroll
        for (int rt = 0; rt < 2; ++rt)
#pragma unroll
            for (int kt2 = 0; kt2 < 2; ++kt2) {
                union { bf16x8 v; ushort u[8]; } pk;
#pragma unroll
                for (int t = 0; t < 2; ++t)
#pragma unroll
                    for (int r = 0; r < 4; ++r)
                        pk.u[t * 4 + r] = f2bf(st[rt][kt2 * 2 + t][r]);
                pf[rt][kt2] = pk.v;
            }

#pragma unroll
        for (int dt = 0; dt < 4; ++dt)
#pragma unroll
            for (int kt2 = 0; kt2 < 2; ++kt2) {
                const bf16x8 vf = *(const bf16x8*)&vb[koff[dt][kt2]];
#pragma unroll
                for (int rt = 0; rt < 2; ++rt)
                    o[rt][dt] = __builtin_amdgcn_mfma_f32_16x16x32_bf16(pf[rt][kt2], vf, o[rt][dt], 0, 0, 0);
            }
    }

    const int b = bh >> 4;
    const int h = bh & 15;
#pragma unroll
    for (int rt = 0; rt < 2; ++rt) {
        const float linv_me = 1.0f / l_[rt];
#pragma unroll
        for (int r = 0; r < 4; ++r) {
            const float lr = __shfl(linv_me, lq * 4 + r, 64);
            const int srow_ = q0 + w * 32 + rt * 16 + lq * 4 + r;
            const size_t base = ((size_t)b * SEQ + srow_) * DIMSZ + h * HDIM;
#pragma unroll
            for (int dt = 0; dt < 4; ++dt) {
                const float v = o[rt][dt][r] * lr;
                const unsigned uv = __float_as_uint(v);
                CTXhi[base + dt * 16 + lm] = (ushort)(uv >> 16);
                const float res = v - __uint_as_float(uv & 0xFFFF0000u);
                CTXlo[base + dt * 16 + lm] = (ushort)(__float_as_uint(res) >> 16);
            }
        }
    }
}

// ---------------------------------------------------------------------------
// Output projection: pre-split bf16 operands, pure-gld16 double-buffered.
// 64x128 tiles -> 512 blocks; 48KB LDS -> 3 blocks/CU.
// ---------------------------------------------------------------------------
__global__ __launch_bounds__(256) void oproj_gemm(
    const ushort* __restrict__ Ahi_g, const ushort* __restrict__ Alo_g,
    const ushort* __restrict__ Bhi_g, const ushort* __restrict__ Blo_g,
    const float* __restrict__ bias, float* __restrict__ out)
{
    // per buffer: Ah[2048] Al[2048] Bh[4096] Bl[4096] ushorts = 24KB; x2 = 48KB
    __shared__ __align__(16) ushort smem[2][12288];

    const int tid = threadIdx.x;
    const int wave = tid >> 6;
    const int lane = tid & 63;
    const int lm = lane & 15;
    const int lq = lane >> 4;
    const int wy = wave >> 1;
    const int wx = wave & 1;
    const int m0 = blockIdx.x * 64;
    const int n0 = blockIdx.y * 128;

    const int c = tid & 3;
    const int r0 = tid >> 2;
    const int g = c ^ swz(r0 & 15);
    const ushort* gah = Ahi_g + (size_t)(m0 + r0) * DIMSZ + g * 8;
    const ushort* gal = Alo_g + (size_t)(m0 + r0) * DIMSZ + g * 8;
    const ushort* gbh = Bhi_g + (size_t)(n0 + r0) * DIMSZ + g * 8;
    const ushort* gbl = Blo_g + (size_t)(n0 + r0) * DIMSZ + g * 8;
    const int wofs = wave * 512;

    const int fo = lm * 32 + (((lq ^ swz(lm)) & 3) << 3);
    int aofs[2], bofs[4];
#pragma unroll
    for (int i = 0; i < 2; ++i) aofs[i] = (wy * 32 + i * 16) * 32 + fo;
#pragma unroll
    for (int j = 0; j < 4; ++j) bofs[j] = (wx * 64 + j * 16) * 32 + fo;

    f32x4 acc[2][4] = {};

    {
        ushort* b0 = &smem[0][0];
        gld16(gah, b0 + wofs);
        gld16(gal, b0 + 2048 + wofs);
        gld16(gbh, b0 + 4096 + wofs);   gld16(gbh + 64 * DIMSZ, b0 + 4096 + 2048 + wofs);
        gld16(gbl, b0 + 8192 + wofs);   gld16(gbl + 64 * DIMSZ, b0 + 8192 + 2048 + wofs);
    }

    for (int kk = 0; kk < 32; ++kk) {
        __syncthreads();

        if (kk + 1 < 32) {
            const int k0 = (kk + 1) * 32;
            ushort* nb = &smem[(kk + 1) & 1][0];
            gld16(gah + k0, nb + wofs);
            gld16(gal + k0, nb + 2048 + wofs);
            gld16(gbh + k0, nb + 4096 + wofs);   gld16(gbh + 64 * DIMSZ + k0, nb + 4096 + 2048 + wofs);
            gld16(gbl + k0, nb + 8192 + wofs);   gld16(gbl + 64 * DIMSZ + k0, nb + 8192 + 2048 + wofs);
        }

        const ushort* Ah = &smem[kk & 1][0];
        const ushort* Al = Ah + 2048;
        const ushort* Bh = Ah + 4096;
        const ushort* Bl = Ah + 8192;

        bf16x8 ahf[2], alf[2], bhf[4], blf[4];
#pragma unroll
        for (int i = 0; i < 2; ++i) {
            ahf[i] = *(const bf16x8*)&Ah[aofs[i]];
            alf[i] = *(const bf16x8*)&Al[aofs[i]];
        }
#pragma unroll
        for (int j = 0; j < 4; ++j) {
            bhf[j] = *(const bf16x8*)&Bh[bofs[j]];
            blf[j] = *(const bf16x8*)&Bl[bofs[j]];
        }
#pragma unroll
        for (int i = 0; i < 2; ++i)
#pragma unroll
            for (int j = 0; j < 4; ++j) {
                acc[i][j] = __builtin_amdgcn_mfma_f32_16x16x32_bf16(ahf[i], bhf[j], acc[i][j], 0, 0, 0);
                acc[i][j] = __builtin_amdgcn_mfma_f32_16x16x32_bf16(ahf[i], blf[j], acc[i][j], 0, 0, 0);
                acc[i][j] = __builtin_amdgcn_mfma_f32_16x16x32_bf16(alf[i], bhf[j], acc[i][j], 0, 0, 0);
            }
    }

#pragma unroll
    for (int j = 0; j < 4; ++j) {
        const int nc = n0 + wx * 64 + j * 16 + lm;
        const float bb = bias[nc];
#pragma unroll
        for (int i = 0; i < 2; ++i) {
            const int mb = m0 + wy * 32 + i * 16 + lq * 4;
#pragma unroll
            for (int rr = 0; rr < 4; ++rr)
                out[(size_t)(mb + rr) * DIMSZ + nc] = acc[i][j][rr] + bb;
        }
    }
}

// ---------------------------------------------------------------------------
extern "C" void kernel_launch(void* const* d_in, const int* in_sizes, int n_in,
                              void* d_out, int out_size, void* d_ws, size_t ws_size,
                              hipStream_t stream)
{
    const float* x  = (const float*)d_in[0];
    const float* Wq = (const float*)d_in[1];
    const float* bq = (const float*)d_in[2];
    const float* Wk = (const float*)d_in[3];
    const float* bk = (const float*)d_in[4];
    const float* Wv = (const float*)d_in[5];
    const float* bv = (const float*)d_in[6];
    const float* Wo = (const float*)d_in[7];
    const float* bo = (const float*)d_in[8];
    float* out = (float*)d_out;

    const size_t elems = (size_t)NROWS * DIMSZ;   // 4M
    ushort* Qb    = (ushort*)d_ws;                // 8MB
    ushort* Kb    = Qb + elems;                   // 8MB
    ushort* Vt    = Kb + elems;                   // 8MB
    ushort* CTXhi = Vt + elems;                   // 8MB  (overlay: Xhi)
    ushort* CTXlo = CTXhi + elems;                // 8MB  (overlay: Xlo)
    ushort* Whi   = CTXlo + elems;                // 6MB
    ushort* Wlo   = Whi + 3 * (1 << 20);          // 6MB
    ushort* Wohi  = Wlo + 3 * (1 << 20);          // 2MB
    ushort* Wolo  = Wohi + (1 << 20);             // 2MB  (peak 56MB)
    ushort* Xhi   = CTXhi;                        // dead before flash writes CTX
    ushort* Xlo   = CTXlo;

    convert_w<<<2048, 256, 0, stream>>>(x, Xhi, Xlo);
    convert_w<<<512, 256, 0, stream>>>(Wq, Whi, Wlo);
    convert_w<<<512, 256, 0, stream>>>(Wk, Whi + (1 << 20), Wlo + (1 << 20));
    convert_w<<<512, 256, 0, stream>>>(Wv, Whi + 2 * (1 << 20), Wlo + 2 * (1 << 20));
    convert_w<<<512, 256, 0, stream>>>(Wo, Wohi, Wolo);

    qkv_gemm<<<dim3(32, 24), 256, 0, stream>>>(Xhi, Xlo, Whi, Wlo, bq, bk, bv, Qb, Kb, Vt);

    flash_attn_mfma<<<dim3(SEQ / 128, BATCH * NHEAD), 256, 0, stream>>>(Qb, Kb, Vt, CTXhi, CTXlo);

    oproj_gemm<<<dim3(64, 8), 256, 0, stream>>>(CTXhi, CTXlo, Wohi, Wolo, bo, out);
}